// Round 4
// baseline (1214.101 us; speedup 1.0000x reference)
//
#include <hip/hip_runtime.h>

#define N_NODES 100000
#define N_EDGES 1000000
#define IN_CH 128
#define HID_CH 64
#define N_CLS 40

#define NBUCK 782              // ceil(100000 / 128) buckets of 128 target cols

static inline int cdiv(int a, int b) { return (a + b - 1) / b; }

// ---------------- bucket partition (col >> 7), pass 1: counts ----------------

__global__ __launch_bounds__(256)
void bucket_count_kernel(const int* __restrict__ cols, int* __restrict__ gcount, int E) {
    __shared__ int hist[NBUCK];
    for (int i = threadIdx.x; i < NBUCK; i += 256) hist[i] = 0;
    __syncthreads();
    int per = (E + gridDim.x - 1) / gridDim.x;
    int s = blockIdx.x * per;
    int e = min(E, s + per);
    for (int j = s + threadIdx.x; j < e; j += 256)
        atomicAdd(&hist[cols[j] >> 7], 1);
    __syncthreads();
    for (int i = threadIdx.x; i < NBUCK; i += 256)
        if (hist[i]) atomicAdd(&gcount[i], hist[i]);
}

// ---------------- scan 782 bucket counts -> boff[NBUCK+1], gcursor ----------------

__global__ __launch_bounds__(1024)
void scan_bucket_kernel(const int* __restrict__ gcount, int* __restrict__ boff,
                        int* __restrict__ gcursor) {
    __shared__ int part[1024];
    int t = threadIdx.x;
    part[t] = (t < NBUCK) ? gcount[t] : 0;
    __syncthreads();
    for (int off = 1; off < 1024; off <<= 1) {
        int v = (t >= off) ? part[t - off] : 0;
        __syncthreads();
        part[t] += v;
        __syncthreads();
    }
    int excl = (t > 0) ? part[t - 1] : 0;
    if (t < NBUCK) { boff[t] = excl; gcursor[t] = excl; }
    if (t == NBUCK) boff[NBUCK] = part[NBUCK - 1];
}

// ---------------- pass 2: scatter edges into bucket order, packed (row<<7 | col&127) ----------------

__global__ __launch_bounds__(256)
void bucket_scatter_kernel(const int* __restrict__ rows, const int* __restrict__ cols,
                           int* __restrict__ gcursor, int* __restrict__ pedge, int E) {
    __shared__ int cur[NBUCK];
    for (int i = threadIdx.x; i < NBUCK; i += 256) cur[i] = 0;
    __syncthreads();
    int per = (E + gridDim.x - 1) / gridDim.x;
    int s = blockIdx.x * per;
    int e = min(E, s + per);
    // local histogram
    for (int j = s + threadIdx.x; j < e; j += 256)
        atomicAdd(&cur[cols[j] >> 7], 1);
    __syncthreads();
    // reserve global ranges per bucket; cur becomes the running cursor (base)
    for (int i = threadIdx.x; i < NBUCK; i += 256) {
        int h = cur[i];
        cur[i] = h ? atomicAdd(&gcursor[i], h) : 0;
    }
    __syncthreads();
    // scatter
    for (int j = s + threadIdx.x; j < e; j += 256) {
        int c = cols[j];
        int pos = atomicAdd(&cur[c >> 7], 1);     // LDS returning atomic
        pedge[pos] = (rows[j] << 7) | (c & 127);
    }
}

// ---------------- per-bucket degree -> dinv (LDS atomics only) ----------------

__global__ __launch_bounds__(256)
void bucket_deg_kernel(const int* __restrict__ boff, const int* __restrict__ pedge,
                       float* __restrict__ dinv) {
    __shared__ int cnt[128];
    int b = blockIdx.x, t = threadIdx.x;
    if (t < 128) cnt[t] = 0;
    __syncthreads();
    int e0 = boff[b], e1 = boff[b + 1];
    for (int j = e0 + t; j < e1; j += 256)
        atomicAdd(&cnt[pedge[j] & 127], 1);
    __syncthreads();
    if (t < 128) {
        int node = b * 128 + t;
        if (node < N_NODES)
            dinv[node] = cnt[t] ? rsqrtf((float)cnt[t]) : 0.f;
    }
}

// ---------------- fused GEMM:  Y1 = X@W1 ; Y2 = X@W2 + Bias  (one pass over X) ----------------

template<int K, int C1, int C2, int RPT, int CPT>
__launch_bounds__(256)
__global__ void gemm_fused_kernel(const float* __restrict__ X,
                                  const float* __restrict__ W1,
                                  const float* __restrict__ W2,
                                  const float* __restrict__ Bias,
                                  float* __restrict__ Y1, float* __restrict__ Y2, int N) {
    constexpr int CT = C1 + C2;
    constexpr int KC = 64;
    constexpr int NCHUNK = K / KC;
    constexpr int NCOLG = CT / CPT;
    constexpr int NROWG = 64 / RPT;
    static_assert(NCOLG * NROWG == 256, "need 256 threads");
    static_assert(C1 % 4 == 0 && C2 % 4 == 0 && CT % 4 == 0, "vec4 staging");

    __shared__ float wl[KC][CT];
    __shared__ float xs[64][KC + 4];

    const int tid = threadIdx.x;
    const int r0 = blockIdx.x * 64;
    const int tcol = tid % NCOLG;
    const int trow = tid / NCOLG;
    const int cbase = tcol * CPT;
    const int rbase = trow * RPT;

    float acc[RPT][CPT];
#pragma unroll
    for (int i = 0; i < RPT; ++i)
#pragma unroll
        for (int j = 0; j < CPT; ++j) acc[i][j] = 0.f;

    for (int ch = 0; ch < NCHUNK; ++ch) {
        __syncthreads();
        // stage weight chunk [KC][CT] from W1|W2
        constexpr int WF4 = KC * CT / 4;
        for (int i = tid; i < WF4; i += 256) {
            int kk = i / (CT / 4);
            int f = i - kk * (CT / 4);
            int k = ch * KC + kk;
            float4 v;
            if (f < C1 / 4) v = *reinterpret_cast<const float4*>(&W1[(size_t)k * C1 + f * 4]);
            else            v = *reinterpret_cast<const float4*>(&W2[(size_t)k * C2 + (f - C1 / 4) * 4]);
            *reinterpret_cast<float4*>(&wl[kk][f * 4]) = v;
        }
        // stage X chunk [64][KC]
        for (int i = tid; i < 1024; i += 256) {
            int rr = i >> 4;
            int k4 = i & 15;
            float4 v = make_float4(0.f, 0.f, 0.f, 0.f);
            int gr = r0 + rr;
            if (gr < N)
                v = *reinterpret_cast<const float4*>(&X[(size_t)gr * K + ch * KC + k4 * 4]);
            *reinterpret_cast<float4*>(&xs[rr][k4 * 4]) = v;
        }
        __syncthreads();
#pragma unroll
        for (int kk = 0; kk < KC; ++kk) {
            float xv[RPT];
#pragma unroll
            for (int i = 0; i < RPT; ++i) xv[i] = xs[rbase + i][kk];
            float wv[CPT];
#pragma unroll
            for (int j = 0; j < CPT; ++j) wv[j] = wl[kk][cbase + j];
#pragma unroll
            for (int i = 0; i < RPT; ++i)
#pragma unroll
                for (int j = 0; j < CPT; ++j)
                    acc[i][j] = fmaf(xv[i], wv[j], acc[i][j]);
        }
    }

#pragma unroll
    for (int i = 0; i < RPT; ++i) {
        int r = r0 + rbase + i;
        if (r < N) {
#pragma unroll
            for (int j = 0; j < CPT; ++j) {
                int c = cbase + j;
                float v = acc[i][j];
                if (c < C1) Y1[(size_t)r * C1 + c] = v;
                else        Y2[(size_t)r * C2 + (c - C1)] = v + Bias[c - C1];
            }
        }
    }
}

// ---------------- bucketed aggregation:  Y[node] = relu(Y[node] + sum norm*H[row]) ----------------
// One block per bucket of 128 target nodes; accumulator tile lives in LDS.

template<int C, int TPE>
__launch_bounds__(256)
__global__ void agg_kernel(const int* __restrict__ boff, const int* __restrict__ pedge,
                           const float* __restrict__ dinv,
                           const float* __restrict__ H, float* __restrict__ Y, int N) {
    constexpr int STRIDE = C + 1;
    constexpr int C4 = C / 4;
    constexpr int EPB = 256 / TPE;          // edges in flight per block
    __shared__ float tile[128 * STRIDE];
    __shared__ float dloc[128];

    int b = blockIdx.x, t = threadIdx.x;
    int base = b * 128;
    for (int i = t; i < 128 * STRIDE; i += 256) tile[i] = 0.f;
    if (t < 128) {
        int node = base + t;
        dloc[t] = (node < N) ? dinv[node] : 0.f;
    }
    __syncthreads();

    int e0 = boff[b], e1 = boff[b + 1];
    int eg = t / TPE;
    int lane = t - eg * TPE;
    const float4* H4 = reinterpret_cast<const float4*>(H);

    if (eg < EPB) {
        for (int j = e0 + eg; j < e1; j += EPB) {
            int p = pedge[j];
            int row = p >> 7;
            int c = p & 127;
            float nv = dloc[c] * dinv[row];
            float4 hv = H4[(size_t)row * C4 + lane];
            float* dst = &tile[c * STRIDE + lane * 4];
            atomicAdd(dst + 0, nv * hv.x);
            atomicAdd(dst + 1, nv * hv.y);
            atomicAdd(dst + 2, nv * hv.z);
            atomicAdd(dst + 3, nv * hv.w);
        }
    }
    __syncthreads();

    // epilogue: Y = relu(Y + tile), coalesced
    float4* Y4 = reinterpret_cast<float4*>(Y);
    for (int idx = t; idx < 128 * C4; idx += 256) {
        int c = idx / C4;
        int f4 = idx - c * C4;
        int node = base + c;
        if (node < N) {
            size_t yi = (size_t)node * C4 + f4;
            float4 y = Y4[yi];
            const float* src = &tile[c * STRIDE + f4 * 4];
            y.x = fmaxf(y.x + src[0], 0.f);
            y.y = fmaxf(y.y + src[1], 0.f);
            y.z = fmaxf(y.z + src[2], 0.f);
            y.w = fmaxf(y.w + src[3], 0.f);
            Y4[yi] = y;
        }
    }
}

// ---------------- launcher ----------------

extern "C" void kernel_launch(void* const* d_in, const int* in_sizes, int n_in,
                              void* d_out, int out_size, void* d_ws, size_t ws_size,
                              hipStream_t stream) {
    const float* x       = (const float*)d_in[0];
    const int*   eidx    = (const int*)d_in[1];
    const float* w1_init = (const float*)d_in[2];
    const float* w1_root = (const float*)d_in[3];
    const float* b1      = (const float*)d_in[4];
    const float* w2_init = (const float*)d_in[5];
    const float* w2_root = (const float*)d_in[6];
    const float* b2      = (const float*)d_in[7];
    float* out = (float*)d_out;

    const int* rows = eidx;                // edge_index[0] (source)
    const int* cols = eidx + N_EDGES;      // edge_index[1] (target)

    // workspace layout (4-byte units)
    int* wsi = (int*)d_ws;
    int*   gcount  = wsi;                  //     784
    int*   boff    = wsi + 784;            //     788 (NBUCK+1 = 783)
    int*   gcursor = wsi + 1572;           //     788
    float* dinv    = (float*)(wsi + 2360); // 100,000
    int*   pedge   = wsi + 102360;         // 1,000,000
    float* h0      = (float*)(wsi + 1102360);  // 6,400,000 (reused as h2)
    float* agg1    = (float*)(wsi + 7502360);  // 6,400,000
    float* h2      = h0;
    // total 13,902,360 * 4 B = 55.6 MB

    // ---- graph prep: bucket partition + dinv ----
    hipMemsetAsync(gcount, 0, 784 * sizeof(int), stream);
    bucket_count_kernel<<<128, 256, 0, stream>>>(cols, gcount, N_EDGES);
    scan_bucket_kernel<<<1, 1024, 0, stream>>>(gcount, boff, gcursor);
    bucket_scatter_kernel<<<128, 256, 0, stream>>>(rows, cols, gcursor, pedge, N_EDGES);
    bucket_deg_kernel<<<NBUCK, 256, 0, stream>>>(boff, pedge, dinv);

    const int GGRID = cdiv(N_NODES, 64);   // 1563

    // ---- layer 1 ----
    gemm_fused_kernel<IN_CH, HID_CH, HID_CH, 4, 8><<<GGRID, 256, 0, stream>>>(
        x, w1_init, w1_root, b1, h0, agg1, N_NODES);
    agg_kernel<HID_CH, HID_CH / 4><<<NBUCK, 256, 0, stream>>>(
        boff, pedge, dinv, h0, agg1, N_NODES);

    // ---- layer 2 ----
    gemm_fused_kernel<HID_CH, N_CLS, N_CLS, 4, 5><<<GGRID, 256, 0, stream>>>(
        agg1, w2_init, w2_root, b2, h2, out, N_NODES);
    agg_kernel<N_CLS, N_CLS / 4><<<NBUCK, 256, 0, stream>>>(
        boff, pedge, dinv, h2, out, N_NODES);
}

// Round 5
// 627.837 us; speedup vs baseline: 1.9338x; 1.9338x over previous
//
#include <hip/hip_runtime.h>

#define N_NODES 100000
#define N_EDGES 1000000
#define IN_CH 128
#define HID_CH 64
#define N_CLS 40

#define NBUCK 782              // ceil(100000 / 128) buckets of 128 target cols

static inline int cdiv(int a, int b) { return (a + b - 1) / b; }

// ---------------- bucket partition (col >> 7), pass 1: counts ----------------

__global__ __launch_bounds__(256)
void bucket_count_kernel(const int* __restrict__ cols, int* __restrict__ gcount, int E) {
    __shared__ int hist[NBUCK];
    for (int i = threadIdx.x; i < NBUCK; i += 256) hist[i] = 0;
    __syncthreads();
    int per = (E + gridDim.x - 1) / gridDim.x;
    int s = blockIdx.x * per;
    int e = min(E, s + per);
    for (int j = s + threadIdx.x; j < e; j += 256)
        atomicAdd(&hist[cols[j] >> 7], 1);
    __syncthreads();
    for (int i = threadIdx.x; i < NBUCK; i += 256)
        if (hist[i]) atomicAdd(&gcount[i], hist[i]);
}

// ---------------- scan 782 bucket counts -> boff[NBUCK+1], gcursor; offsets[N]=E ----------------

__global__ __launch_bounds__(1024)
void scan_bucket_kernel(const int* __restrict__ gcount, int* __restrict__ boff,
                        int* __restrict__ gcursor, int* __restrict__ offsets) {
    __shared__ int part[1024];
    int t = threadIdx.x;
    part[t] = (t < NBUCK) ? gcount[t] : 0;
    __syncthreads();
    for (int off = 1; off < 1024; off <<= 1) {
        int v = (t >= off) ? part[t - off] : 0;
        __syncthreads();
        part[t] += v;
        __syncthreads();
    }
    int excl = (t > 0) ? part[t - 1] : 0;
    if (t < NBUCK) { boff[t] = excl; gcursor[t] = excl; }
    if (t == NBUCK) { boff[NBUCK] = excl; offsets[N_NODES] = excl; }
}

// ---------------- pass 2: scatter edges into bucket order, packed (row<<7 | col&127) ----------------

__global__ __launch_bounds__(256)
void bucket_scatter_kernel(const int* __restrict__ rows, const int* __restrict__ cols,
                           int* __restrict__ gcursor, int* __restrict__ pedge, int E) {
    __shared__ int cur[NBUCK];
    for (int i = threadIdx.x; i < NBUCK; i += 256) cur[i] = 0;
    __syncthreads();
    int per = (E + gridDim.x - 1) / gridDim.x;
    int s = blockIdx.x * per;
    int e = min(E, s + per);
    // local histogram
    for (int j = s + threadIdx.x; j < e; j += 256)
        atomicAdd(&cur[cols[j] >> 7], 1);
    __syncthreads();
    // reserve global ranges per bucket; cur becomes the running local cursor
    for (int i = threadIdx.x; i < NBUCK; i += 256) {
        int h = cur[i];
        cur[i] = h ? atomicAdd(&gcursor[i], h) : 0;
    }
    __syncthreads();
    // scatter
    for (int j = s + threadIdx.x; j < e; j += 256) {
        int c = cols[j];
        int pos = atomicAdd(&cur[c >> 7], 1);     // LDS returning atomic
        pedge[pos] = (rows[j] << 7) | (c & 127);
    }
}

// ---------------- per-bucket counting sort -> srow (CSR), offsets, dinv ----------------

__global__ __launch_bounds__(256)
void bucket_sort_kernel(const int* __restrict__ boff, const int* __restrict__ pedge,
                        int* __restrict__ srow, int* __restrict__ offsets,
                        float* __restrict__ dinv) {
    __shared__ int cnt[128];
    __shared__ int scn[128];
    __shared__ int cur[128];
    int b = blockIdx.x, t = threadIdx.x;
    if (t < 128) cnt[t] = 0;
    __syncthreads();
    int e0 = boff[b], e1 = boff[b + 1];
    for (int j = e0 + t; j < e1; j += 256)
        atomicAdd(&cnt[pedge[j] & 127], 1);
    __syncthreads();
    if (t < 128) scn[t] = cnt[t];
    __syncthreads();
    for (int off = 1; off < 128; off <<= 1) {
        int v = 0;
        if (t < 128 && t >= off) v = scn[t - off];
        __syncthreads();
        if (t < 128) scn[t] += v;
        __syncthreads();
    }
    if (t < 128) {
        int excl = (t > 0) ? scn[t - 1] : 0;
        cur[t] = excl;
        int node = b * 128 + t;
        if (node < N_NODES) {
            offsets[node] = e0 + excl;
            dinv[node] = cnt[t] ? rsqrtf((float)cnt[t]) : 0.f;
        }
    }
    __syncthreads();
    for (int j = e0 + t; j < e1; j += 256) {
        int p = pedge[j];
        int pos = atomicAdd(&cur[p & 127], 1);
        srow[e0 + pos] = p >> 7;
    }
}

// ---------------- fused GEMM:  Y1 = X@W1 ; Y2 = X@W2 + Bias  (one pass over X) ----------------

template<int K, int C1, int C2, int RPT, int CPT>
__launch_bounds__(256)
__global__ void gemm_fused_kernel(const float* __restrict__ X,
                                  const float* __restrict__ W1,
                                  const float* __restrict__ W2,
                                  const float* __restrict__ Bias,
                                  float* __restrict__ Y1, float* __restrict__ Y2, int N) {
    constexpr int CT = C1 + C2;
    constexpr int KC = 64;
    constexpr int NCHUNK = K / KC;
    constexpr int NCOLG = CT / CPT;
    constexpr int NROWG = 64 / RPT;
    static_assert(NCOLG * NROWG == 256, "need 256 threads");
    static_assert(C1 % 4 == 0 && C2 % 4 == 0 && CT % 4 == 0, "vec4 staging");

    __shared__ float wl[KC][CT];
    __shared__ float xs[64][KC + 4];

    const int tid = threadIdx.x;
    const int r0 = blockIdx.x * 64;
    const int tcol = tid % NCOLG;
    const int trow = tid / NCOLG;
    const int cbase = tcol * CPT;
    const int rbase = trow * RPT;

    float acc[RPT][CPT];
#pragma unroll
    for (int i = 0; i < RPT; ++i)
#pragma unroll
        for (int j = 0; j < CPT; ++j) acc[i][j] = 0.f;

    for (int ch = 0; ch < NCHUNK; ++ch) {
        __syncthreads();
        // stage weight chunk [KC][CT] from W1|W2
        constexpr int WF4 = KC * CT / 4;
        for (int i = tid; i < WF4; i += 256) {
            int kk = i / (CT / 4);
            int f = i - kk * (CT / 4);
            int k = ch * KC + kk;
            float4 v;
            if (f < C1 / 4) v = *reinterpret_cast<const float4*>(&W1[(size_t)k * C1 + f * 4]);
            else            v = *reinterpret_cast<const float4*>(&W2[(size_t)k * C2 + (f - C1 / 4) * 4]);
            *reinterpret_cast<float4*>(&wl[kk][f * 4]) = v;
        }
        // stage X chunk [64][KC]
        for (int i = tid; i < 1024; i += 256) {
            int rr = i >> 4;
            int k4 = i & 15;
            float4 v = make_float4(0.f, 0.f, 0.f, 0.f);
            int gr = r0 + rr;
            if (gr < N)
                v = *reinterpret_cast<const float4*>(&X[(size_t)gr * K + ch * KC + k4 * 4]);
            *reinterpret_cast<float4*>(&xs[rr][k4 * 4]) = v;
        }
        __syncthreads();
#pragma unroll
        for (int kk = 0; kk < KC; ++kk) {
            float xv[RPT];
#pragma unroll
            for (int i = 0; i < RPT; ++i) xv[i] = xs[rbase + i][kk];
            float wv[CPT];
#pragma unroll
            for (int j = 0; j < CPT; ++j) wv[j] = wl[kk][cbase + j];
#pragma unroll
            for (int i = 0; i < RPT; ++i)
#pragma unroll
                for (int j = 0; j < CPT; ++j)
                    acc[i][j] = fmaf(xv[i], wv[j], acc[i][j]);
        }
    }

#pragma unroll
    for (int i = 0; i < RPT; ++i) {
        int r = r0 + rbase + i;
        if (r < N) {
#pragma unroll
            for (int j = 0; j < CPT; ++j) {
                int c = cbase + j;
                float v = acc[i][j];
                if (c < C1) Y1[(size_t)r * C1 + c] = v;
                else        Y2[(size_t)r * C2 + (c - C1)] = v + Bias[c - C1];
            }
        }
    }
}

// ---------------- pull aggregation:  Y[node] = relu(Y[node] + sum_e norm * H[srow]) ----------------

template<int C>
__launch_bounds__(256)
__global__ void pull_kernel(const int* __restrict__ offsets,
                            const int* __restrict__ srow,
                            const float* __restrict__ dinv,
                            const float* __restrict__ H,
                            float* __restrict__ Y, int N) {
    constexpr int TPE = C / 4;
    int gid = blockIdx.x * blockDim.x + threadIdx.x;
    int node = gid / TPE;
    int lane = gid - node * TPE;
    if (node >= N) return;

    int e0 = offsets[node];
    int e1 = offsets[node + 1];
    float dc = dinv[node];

    const float4* H4 = reinterpret_cast<const float4*>(H);
    float4 acc = make_float4(0.f, 0.f, 0.f, 0.f);
    for (int j = e0; j < e1; ++j) {
        int r = srow[j];
        float nv = dc * dinv[r];
        float4 hv = H4[(size_t)r * TPE + lane];
        acc.x = fmaf(nv, hv.x, acc.x);
        acc.y = fmaf(nv, hv.y, acc.y);
        acc.z = fmaf(nv, hv.z, acc.z);
        acc.w = fmaf(nv, hv.w, acc.w);
    }

    float4* Y4 = reinterpret_cast<float4*>(Y);
    size_t yi = (size_t)node * TPE + lane;
    float4 y = Y4[yi];
    y.x = fmaxf(y.x + acc.x, 0.f);
    y.y = fmaxf(y.y + acc.y, 0.f);
    y.z = fmaxf(y.z + acc.z, 0.f);
    y.w = fmaxf(y.w + acc.w, 0.f);
    Y4[yi] = y;
}

// ---------------- launcher ----------------

extern "C" void kernel_launch(void* const* d_in, const int* in_sizes, int n_in,
                              void* d_out, int out_size, void* d_ws, size_t ws_size,
                              hipStream_t stream) {
    const float* x       = (const float*)d_in[0];
    const int*   eidx    = (const int*)d_in[1];
    const float* w1_init = (const float*)d_in[2];
    const float* w1_root = (const float*)d_in[3];
    const float* b1      = (const float*)d_in[4];
    const float* w2_init = (const float*)d_in[5];
    const float* w2_root = (const float*)d_in[6];
    const float* b2      = (const float*)d_in[7];
    float* out = (float*)d_out;

    const int* rows = eidx;                // edge_index[0] (source)
    const int* cols = eidx + N_EDGES;      // edge_index[1] (target)

    // workspace layout (4-byte units)
    int* wsi = (int*)d_ws;
    int*   gcount  = wsi;                       //     784
    int*   boff    = wsi + 784;                 //     788 (NBUCK+1 = 783 used)
    int*   gcursor = wsi + 1572;                //     788
    float* dinv    = (float*)(wsi + 2360);      // 100,000
    int*   offsets = wsi + 102360;              // 100,004 (N_NODES+1 used)
    int*   srow    = wsi + 202364;              // 1,000,000
    float* h0      = (float*)(wsi + 1202364);   // 6,400,000  (reused as h2)
    int*   pedge   = wsi + 1202364;             // aliases h0: dead before gemm L1 runs
    float* agg1    = (float*)(wsi + 7602364);   // 6,400,000
    float* h2      = h0;
    // total 14,002,364 * 4 B = 56.0 MB

    // ---- graph prep: bucket partition -> sorted CSR + dinv (no global per-edge atomics) ----
    hipMemsetAsync(gcount, 0, 784 * sizeof(int), stream);
    bucket_count_kernel<<<128, 256, 0, stream>>>(cols, gcount, N_EDGES);
    scan_bucket_kernel<<<1, 1024, 0, stream>>>(gcount, boff, gcursor, offsets);
    bucket_scatter_kernel<<<128, 256, 0, stream>>>(rows, cols, gcursor, pedge, N_EDGES);
    bucket_sort_kernel<<<NBUCK, 256, 0, stream>>>(boff, pedge, srow, offsets, dinv);

    const int GGRID = cdiv(N_NODES, 64);   // 1563

    // ---- layer 1 ----
    gemm_fused_kernel<IN_CH, HID_CH, HID_CH, 4, 8><<<GGRID, 256, 0, stream>>>(
        x, w1_init, w1_root, b1, h0, agg1, N_NODES);
    pull_kernel<HID_CH><<<cdiv(N_NODES * (HID_CH / 4), 256), 256, 0, stream>>>(
        offsets, srow, dinv, h0, agg1, N_NODES);

    // ---- layer 2 ----
    gemm_fused_kernel<HID_CH, N_CLS, N_CLS, 4, 5><<<GGRID, 256, 0, stream>>>(
        agg1, w2_init, w2_root, b2, h2, out, N_NODES);
    pull_kernel<N_CLS><<<cdiv(N_NODES * (N_CLS / 4), 256), 256, 0, stream>>>(
        offsets, srow, dinv, h2, out, N_NODES);
}

// Round 6
// 336.789 us; speedup vs baseline: 3.6049x; 1.8642x over previous
//
#include <hip/hip_runtime.h>

#define N_NODES 100000
#define N_EDGES 1000000
#define IN_CH 128
#define HID_CH 64
#define N_CLS 40

#define NBUCK 782              // ceil(100000 / 128) buckets of 128 target cols

static inline int cdiv(int a, int b) { return (a + b - 1) / b; }

// ---------------- bucket partition (col >> 7), pass 1: counts ----------------

__global__ __launch_bounds__(256)
void bucket_count_kernel(const int* __restrict__ cols, int* __restrict__ gcount, int E) {
    __shared__ int hist[NBUCK];
    for (int i = threadIdx.x; i < NBUCK; i += 256) hist[i] = 0;
    __syncthreads();
    int per = (E + gridDim.x - 1) / gridDim.x;
    int s = blockIdx.x * per;
    int e = min(E, s + per);
    for (int j = s + threadIdx.x; j < e; j += 256)
        atomicAdd(&hist[cols[j] >> 7], 1);
    __syncthreads();
    for (int i = threadIdx.x; i < NBUCK; i += 256)
        if (hist[i]) atomicAdd(&gcount[i], hist[i]);
}

// ---------------- scan 782 bucket counts -> boff[NBUCK+1], gcursor; offsets[N]=E ----------------

__global__ __launch_bounds__(1024)
void scan_bucket_kernel(const int* __restrict__ gcount, int* __restrict__ boff,
                        int* __restrict__ gcursor, int* __restrict__ offsets) {
    __shared__ int part[1024];
    int t = threadIdx.x;
    part[t] = (t < NBUCK) ? gcount[t] : 0;
    __syncthreads();
    for (int off = 1; off < 1024; off <<= 1) {
        int v = (t >= off) ? part[t - off] : 0;
        __syncthreads();
        part[t] += v;
        __syncthreads();
    }
    int excl = (t > 0) ? part[t - 1] : 0;
    if (t < NBUCK) { boff[t] = excl; gcursor[t] = excl; }
    if (t == NBUCK) { boff[NBUCK] = excl; offsets[N_NODES] = excl; }
}

// ---------------- pass 2: scatter edges into bucket order, packed (row<<7 | col&127) ----------------

__global__ __launch_bounds__(256)
void bucket_scatter_kernel(const int* __restrict__ rows, const int* __restrict__ cols,
                           int* __restrict__ gcursor, int* __restrict__ pedge, int E) {
    __shared__ int cur[NBUCK];
    for (int i = threadIdx.x; i < NBUCK; i += 256) cur[i] = 0;
    __syncthreads();
    int per = (E + gridDim.x - 1) / gridDim.x;
    int s = blockIdx.x * per;
    int e = min(E, s + per);
    for (int j = s + threadIdx.x; j < e; j += 256)
        atomicAdd(&cur[cols[j] >> 7], 1);
    __syncthreads();
    for (int i = threadIdx.x; i < NBUCK; i += 256) {
        int h = cur[i];
        cur[i] = h ? atomicAdd(&gcursor[i], h) : 0;
    }
    __syncthreads();
    for (int j = s + threadIdx.x; j < e; j += 256) {
        int c = cols[j];
        int pos = atomicAdd(&cur[c >> 7], 1);     // LDS returning atomic
        pedge[pos] = (rows[j] << 7) | (c & 127);
    }
}

// ---------------- per-bucket counting sort -> srow (CSR), offsets, dinv ----------------

__global__ __launch_bounds__(256)
void bucket_sort_kernel(const int* __restrict__ boff, const int* __restrict__ pedge,
                        int* __restrict__ srow, int* __restrict__ offsets,
                        float* __restrict__ dinv) {
    __shared__ int cnt[128];
    __shared__ int scn[128];
    __shared__ int cur[128];
    int b = blockIdx.x, t = threadIdx.x;
    if (t < 128) cnt[t] = 0;
    __syncthreads();
    int e0 = boff[b], e1 = boff[b + 1];
    for (int j = e0 + t; j < e1; j += 256)
        atomicAdd(&cnt[pedge[j] & 127], 1);
    __syncthreads();
    if (t < 128) scn[t] = cnt[t];
    __syncthreads();
    for (int off = 1; off < 128; off <<= 1) {
        int v = 0;
        if (t < 128 && t >= off) v = scn[t - off];
        __syncthreads();
        if (t < 128) scn[t] += v;
        __syncthreads();
    }
    if (t < 128) {
        int excl = (t > 0) ? scn[t - 1] : 0;
        cur[t] = excl;
        int node = b * 128 + t;
        if (node < N_NODES) {
            offsets[node] = e0 + excl;
            dinv[node] = cnt[t] ? rsqrtf((float)cnt[t]) : 0.f;
        }
    }
    __syncthreads();
    for (int j = e0 + t; j < e1; j += 256) {
        int p = pedge[j];
        int pos = atomicAdd(&cur[p & 127], 1);
        srow[e0 + pos] = p >> 7;
    }
}

// ---------------- fused GEMM:  Y1 = X@W1 ; Y2 = X@W2 + Bias (one pass over X) ----------------
// 64-row x CT-col tile per 256-thread block; 16x16 thread grid, RPT=4 rows x CPT cols.
// xst transposed [k][row] so the x-fragment is one aligned ds_read_b128.
// __launch_bounds__(256,4) caps VGPR at 128 -> no spill (round-5 lesson).

template<int K, int C1, int C2>
__launch_bounds__(256, 4)
__global__ void gemm_fused_kernel(const float* __restrict__ X,
                                  const float* __restrict__ W1,
                                  const float* __restrict__ W2,
                                  const float* __restrict__ Bias,
                                  float* __restrict__ Y1, float* __restrict__ Y2, int N) {
    constexpr int CT = C1 + C2;
    constexpr int CPT = CT / 16;           // 8 for L1 (128), 5 for L2 (80)
    constexpr int RPT = 4;
    constexpr int KC = 64;
    constexpr int NCHUNK = K / KC;
    static_assert(CT % 16 == 0 && C1 % 4 == 0 && C2 % 4 == 0, "layout");

    __shared__ float wl[KC][CT];           // weight chunk
    __shared__ float xst[KC][68];          // transposed x tile, stride 68 keeps 16B align

    const int tid = threadIdx.x;
    const int r0 = blockIdx.x * 64;
    const int tcol = tid & 15;             // 16 col-groups
    const int trow = tid >> 4;             // 16 row-groups
    const int cbase = tcol * CPT;
    const int rbase = trow * RPT;

    // preload bias for this thread's columns (registers)
    float bs[CPT];
#pragma unroll
    for (int j = 0; j < CPT; ++j)
        bs[j] = (cbase >= C1) ? Bias[cbase - C1 + j] : 0.f;

    float acc[RPT][CPT];
#pragma unroll
    for (int i = 0; i < RPT; ++i)
#pragma unroll
        for (int j = 0; j < CPT; ++j) acc[i][j] = 0.f;

    for (int ch = 0; ch < NCHUNK; ++ch) {
        __syncthreads();
        // stage weight chunk [KC][CT] from W1 | W2 (two clean loops, no inner branch)
        constexpr int W1F4 = KC * C1 / 4;
        constexpr int W2F4 = KC * C2 / 4;
        for (int i = tid; i < W1F4; i += 256) {
            int kk = i / (C1 / 4);
            int f4 = i - kk * (C1 / 4);
            float4 v = *reinterpret_cast<const float4*>(&W1[(size_t)(ch * KC + kk) * C1 + f4 * 4]);
            *reinterpret_cast<float4*>(&wl[kk][f4 * 4]) = v;
        }
        for (int i = tid; i < W2F4; i += 256) {
            int kk = i / (C2 / 4);
            int f4 = i - kk * (C2 / 4);
            float4 v = *reinterpret_cast<const float4*>(&W2[(size_t)(ch * KC + kk) * C2 + f4 * 4]);
            *reinterpret_cast<float4*>(&wl[kk][C1 + f4 * 4]) = v;
        }
        // stage x tile transposed: [64 rows][KC] -> xst[k][row]
        for (int i = tid; i < 1024; i += 256) {
            int rr = i >> 4;
            int k4 = i & 15;
            int gr = r0 + rr;
            float4 v = make_float4(0.f, 0.f, 0.f, 0.f);
            if (gr < N)
                v = *reinterpret_cast<const float4*>(&X[(size_t)gr * K + ch * KC + k4 * 4]);
            xst[k4 * 4 + 0][rr] = v.x;
            xst[k4 * 4 + 1][rr] = v.y;
            xst[k4 * 4 + 2][rr] = v.z;
            xst[k4 * 4 + 3][rr] = v.w;
        }
        __syncthreads();
#pragma unroll 16
        for (int kk = 0; kk < KC; ++kk) {
            float4 xv = *reinterpret_cast<const float4*>(&xst[kk][rbase]);  // b128
            float wv[CPT];
#pragma unroll
            for (int j = 0; j < CPT; ++j) wv[j] = wl[kk][cbase + j];
#pragma unroll
            for (int j = 0; j < CPT; ++j) {
                acc[0][j] = fmaf(xv.x, wv[j], acc[0][j]);
                acc[1][j] = fmaf(xv.y, wv[j], acc[1][j]);
                acc[2][j] = fmaf(xv.z, wv[j], acc[2][j]);
                acc[3][j] = fmaf(xv.w, wv[j], acc[3][j]);
            }
        }
    }

    // epilogue: each thread's CPT cols are entirely in Y1 or entirely in Y2
#pragma unroll
    for (int i = 0; i < RPT; ++i) {
        int r = r0 + rbase + i;
        if (r >= N) continue;
        if (cbase < C1) {
#pragma unroll
            for (int j = 0; j < CPT; ++j)
                Y1[(size_t)r * C1 + cbase + j] = acc[i][j];
        } else {
#pragma unroll
            for (int j = 0; j < CPT; ++j)
                Y2[(size_t)r * C2 + (cbase - C1) + j] = acc[i][j] + bs[j];
        }
    }
}

// ---------------- pull aggregation:  Y[node] = relu(Y[node] + sum_e norm * H[srow]) ----------------

template<int C>
__launch_bounds__(256)
__global__ void pull_kernel(const int* __restrict__ offsets,
                            const int* __restrict__ srow,
                            const float* __restrict__ dinv,
                            const float* __restrict__ H,
                            float* __restrict__ Y, int N) {
    constexpr int TPE = C / 4;
    int gid = blockIdx.x * blockDim.x + threadIdx.x;
    int node = gid / TPE;
    int lane = gid - node * TPE;
    if (node >= N) return;

    int e0 = offsets[node];
    int e1 = offsets[node + 1];
    float dc = dinv[node];

    const float4* H4 = reinterpret_cast<const float4*>(H);
    float4 acc = make_float4(0.f, 0.f, 0.f, 0.f);
    for (int j = e0; j < e1; ++j) {
        int r = srow[j];
        float nv = dc * dinv[r];
        float4 hv = H4[(size_t)r * TPE + lane];
        acc.x = fmaf(nv, hv.x, acc.x);
        acc.y = fmaf(nv, hv.y, acc.y);
        acc.z = fmaf(nv, hv.z, acc.z);
        acc.w = fmaf(nv, hv.w, acc.w);
    }

    float4* Y4 = reinterpret_cast<float4*>(Y);
    size_t yi = (size_t)node * TPE + lane;
    float4 y = Y4[yi];
    y.x = fmaxf(y.x + acc.x, 0.f);
    y.y = fmaxf(y.y + acc.y, 0.f);
    y.z = fmaxf(y.z + acc.z, 0.f);
    y.w = fmaxf(y.w + acc.w, 0.f);
    Y4[yi] = y;
}

// ---------------- launcher ----------------

extern "C" void kernel_launch(void* const* d_in, const int* in_sizes, int n_in,
                              void* d_out, int out_size, void* d_ws, size_t ws_size,
                              hipStream_t stream) {
    const float* x       = (const float*)d_in[0];
    const int*   eidx    = (const int*)d_in[1];
    const float* w1_init = (const float*)d_in[2];
    const float* w1_root = (const float*)d_in[3];
    const float* b1      = (const float*)d_in[4];
    const float* w2_init = (const float*)d_in[5];
    const float* w2_root = (const float*)d_in[6];
    const float* b2      = (const float*)d_in[7];
    float* out = (float*)d_out;

    const int* rows = eidx;                // edge_index[0] (source)
    const int* cols = eidx + N_EDGES;      // edge_index[1] (target)

    // workspace layout (4-byte units)
    int* wsi = (int*)d_ws;
    int*   gcount  = wsi;                       //     784
    int*   boff    = wsi + 784;                 //     788 (NBUCK+1 = 783 used)
    int*   gcursor = wsi + 1572;                //     788
    float* dinv    = (float*)(wsi + 2360);      // 100,000
    int*   offsets = wsi + 102360;              // 100,004 (N_NODES+1 used)
    int*   srow    = wsi + 202364;              // 1,000,000
    float* h0      = (float*)(wsi + 1202364);   // 6,400,000  (reused as h2)
    int*   pedge   = wsi + 1202364;             // aliases h0: dead before gemm L1 runs
    float* agg1    = (float*)(wsi + 7602364);   // 6,400,000
    float* h2      = h0;
    // total 14,002,364 * 4 B = 56.0 MB

    // ---- graph prep: bucket partition -> sorted CSR + dinv (no global per-edge atomics) ----
    hipMemsetAsync(gcount, 0, 784 * sizeof(int), stream);
    bucket_count_kernel<<<128, 256, 0, stream>>>(cols, gcount, N_EDGES);
    scan_bucket_kernel<<<1, 1024, 0, stream>>>(gcount, boff, gcursor, offsets);
    bucket_scatter_kernel<<<128, 256, 0, stream>>>(rows, cols, gcursor, pedge, N_EDGES);
    bucket_sort_kernel<<<NBUCK, 256, 0, stream>>>(boff, pedge, srow, offsets, dinv);

    const int GGRID = cdiv(N_NODES, 64);   // 1563

    // ---- layer 1 ----
    gemm_fused_kernel<IN_CH, HID_CH, HID_CH><<<GGRID, 256, 0, stream>>>(
        x, w1_init, w1_root, b1, h0, agg1, N_NODES);
    pull_kernel<HID_CH><<<cdiv(N_NODES * (HID_CH / 4), 256), 256, 0, stream>>>(
        offsets, srow, dinv, h0, agg1, N_NODES);

    // ---- layer 2 ----
    gemm_fused_kernel<HID_CH, N_CLS, N_CLS><<<GGRID, 256, 0, stream>>>(
        agg1, w2_init, w2_root, b2, h2, out, N_NODES);
    pull_kernel<N_CLS><<<cdiv(N_NODES * (N_CLS / 4), 256), 256, 0, stream>>>(
        offsets, srow, dinv, h2, out, N_NODES);
}

// Round 7
// 325.603 us; speedup vs baseline: 3.7288x; 1.0344x over previous
//
#include <hip/hip_runtime.h>

#define N_NODES 100000
#define N_EDGES 1000000
#define IN_CH 128
#define HID_CH 64
#define N_CLS 40

#define NBUCK 782              // ceil(100000 / 128) buckets of 128 target cols

static inline int cdiv(int a, int b) { return (a + b - 1) / b; }

// ---------------- bucket partition (col >> 7), pass 1: counts ----------------

__global__ __launch_bounds__(256)
void bucket_count_kernel(const int* __restrict__ cols, int* __restrict__ gcount, int E) {
    __shared__ int hist[NBUCK];
    for (int i = threadIdx.x; i < NBUCK; i += 256) hist[i] = 0;
    __syncthreads();
    int per = (E + gridDim.x - 1) / gridDim.x;
    int s = blockIdx.x * per;
    int e = min(E, s + per);
    for (int j = s + threadIdx.x; j < e; j += 256)
        atomicAdd(&hist[cols[j] >> 7], 1);
    __syncthreads();
    for (int i = threadIdx.x; i < NBUCK; i += 256)
        if (hist[i]) atomicAdd(&gcount[i], hist[i]);
}

// ---------------- scan 782 bucket counts -> boff[NBUCK+1], gcursor; offsets[N]=E ----------------

__global__ __launch_bounds__(1024)
void scan_bucket_kernel(const int* __restrict__ gcount, int* __restrict__ boff,
                        int* __restrict__ gcursor, int* __restrict__ offsets) {
    __shared__ int part[1024];
    int t = threadIdx.x;
    part[t] = (t < NBUCK) ? gcount[t] : 0;
    __syncthreads();
    for (int off = 1; off < 1024; off <<= 1) {
        int v = (t >= off) ? part[t - off] : 0;
        __syncthreads();
        part[t] += v;
        __syncthreads();
    }
    int excl = (t > 0) ? part[t - 1] : 0;
    if (t < NBUCK) { boff[t] = excl; gcursor[t] = excl; }
    if (t == NBUCK) { boff[NBUCK] = excl; offsets[N_NODES] = excl; }
}

// ---------------- pass 2: scatter edges into bucket order, packed (row<<7 | col&127) ----------------

__global__ __launch_bounds__(256)
void bucket_scatter_kernel(const int* __restrict__ rows, const int* __restrict__ cols,
                           int* __restrict__ gcursor, int* __restrict__ pedge, int E) {
    __shared__ int cur[NBUCK];
    for (int i = threadIdx.x; i < NBUCK; i += 256) cur[i] = 0;
    __syncthreads();
    int per = (E + gridDim.x - 1) / gridDim.x;
    int s = blockIdx.x * per;
    int e = min(E, s + per);
    for (int j = s + threadIdx.x; j < e; j += 256)
        atomicAdd(&cur[cols[j] >> 7], 1);
    __syncthreads();
    for (int i = threadIdx.x; i < NBUCK; i += 256) {
        int h = cur[i];
        cur[i] = h ? atomicAdd(&gcursor[i], h) : 0;
    }
    __syncthreads();
    for (int j = s + threadIdx.x; j < e; j += 256) {
        int c = cols[j];
        int pos = atomicAdd(&cur[c >> 7], 1);     // LDS returning atomic
        pedge[pos] = (rows[j] << 7) | (c & 127);
    }
}

// ---------------- per-bucket counting sort -> srow (CSR), offsets, dinv ----------------

__global__ __launch_bounds__(256)
void bucket_sort_kernel(const int* __restrict__ boff, const int* __restrict__ pedge,
                        int* __restrict__ srow, int* __restrict__ offsets,
                        float* __restrict__ dinv) {
    __shared__ int cnt[128];
    __shared__ int scn[128];
    __shared__ int cur[128];
    int b = blockIdx.x, t = threadIdx.x;
    if (t < 128) cnt[t] = 0;
    __syncthreads();
    int e0 = boff[b], e1 = boff[b + 1];
    for (int j = e0 + t; j < e1; j += 256)
        atomicAdd(&cnt[pedge[j] & 127], 1);
    __syncthreads();
    if (t < 128) scn[t] = cnt[t];
    __syncthreads();
    for (int off = 1; off < 128; off <<= 1) {
        int v = 0;
        if (t < 128 && t >= off) v = scn[t - off];
        __syncthreads();
        if (t < 128) scn[t] += v;
        __syncthreads();
    }
    if (t < 128) {
        int excl = (t > 0) ? scn[t - 1] : 0;
        cur[t] = excl;
        int node = b * 128 + t;
        if (node < N_NODES) {
            offsets[node] = e0 + excl;
            dinv[node] = cnt[t] ? rsqrtf((float)cnt[t]) : 0.f;
        }
    }
    __syncthreads();
    for (int j = e0 + t; j < e1; j += 256) {
        int p = pedge[j];
        int pos = atomicAdd(&cur[p & 127], 1);
        srow[e0 + pos] = p >> 7;
    }
}

// ---------------- fused GEMM:  Y1 = X@W1 ; Y2 = X@W2 + Bias (one pass over X) ----------------
// 64-row x CT-col tile per 256-thread block; 16x16 thread grid, RPT=4 rows x CPT cols.
// Row-major xs[64][KC+4] (float4 stores: 0 bank conflicts - round-6 lesson),
// broadcast scalar x-fragment reads, float4 weight-fragment reads when aligned.
// KC=32 keeps LDS ~25 KB -> 6 blocks/CU. __launch_bounds__(256,4) caps VGPR.

template<int K, int C1, int C2>
__launch_bounds__(256, 4)
__global__ void gemm_fused_kernel(const float* __restrict__ X,
                                  const float* __restrict__ W1,
                                  const float* __restrict__ W2,
                                  const float* __restrict__ Bias,
                                  float* __restrict__ Y1, float* __restrict__ Y2, int N) {
    constexpr int CT = C1 + C2;
    constexpr int CPT = CT / 16;           // 8 for L1 (128), 5 for L2 (80)
    constexpr int RPT = 4;
    constexpr int KC = 32;
    constexpr int NCHUNK = K / KC;
    static_assert(CT % 16 == 0 && C1 % 4 == 0 && C2 % 4 == 0, "layout");

    __shared__ float wl[KC][CT];           // weight chunk
    __shared__ float xs[64][KC + 4];       // row-major x tile (pad kills k-stride conflicts)

    const int tid = threadIdx.x;
    const int r0 = blockIdx.x * 64;
    const int tcol = tid & 15;             // 16 col-groups
    const int trow = tid >> 4;             // 16 row-groups
    const int cbase = tcol * CPT;
    const int rbase = trow * RPT;

    float bs[CPT];
#pragma unroll
    for (int j = 0; j < CPT; ++j)
        bs[j] = (cbase >= C1) ? Bias[cbase - C1 + j] : 0.f;

    float acc[RPT][CPT];
#pragma unroll
    for (int i = 0; i < RPT; ++i)
#pragma unroll
        for (int j = 0; j < CPT; ++j) acc[i][j] = 0.f;

    for (int ch = 0; ch < NCHUNK; ++ch) {
        __syncthreads();
        // stage weight chunk [KC][CT] from W1 | W2 (two clean loops, no inner branch)
        constexpr int W1F4 = KC * C1 / 4;
        constexpr int W2F4 = KC * C2 / 4;
        for (int i = tid; i < W1F4; i += 256) {
            int kk = i / (C1 / 4);
            int f4 = i - kk * (C1 / 4);
            float4 v = *reinterpret_cast<const float4*>(&W1[(size_t)(ch * KC + kk) * C1 + f4 * 4]);
            *reinterpret_cast<float4*>(&wl[kk][f4 * 4]) = v;
        }
        for (int i = tid; i < W2F4; i += 256) {
            int kk = i / (C2 / 4);
            int f4 = i - kk * (C2 / 4);
            float4 v = *reinterpret_cast<const float4*>(&W2[(size_t)(ch * KC + kk) * C2 + f4 * 4]);
            *reinterpret_cast<float4*>(&wl[kk][C1 + f4 * 4]) = v;
        }
        // stage x tile row-major: 64 rows x KC floats = 64*KC/4 float4
        constexpr int XF4 = 64 * KC / 4;
        for (int i = tid; i < XF4; i += 256) {
            int rr = i / (KC / 4);
            int k4 = i - rr * (KC / 4);
            int gr = r0 + rr;
            float4 v = make_float4(0.f, 0.f, 0.f, 0.f);
            if (gr < N)
                v = *reinterpret_cast<const float4*>(&X[(size_t)gr * K + ch * KC + k4 * 4]);
            *reinterpret_cast<float4*>(&xs[rr][k4 * 4]) = v;
        }
        __syncthreads();
#pragma unroll 8
        for (int kk = 0; kk < KC; ++kk) {
            float xv[RPT];
#pragma unroll
            for (int i = 0; i < RPT; ++i) xv[i] = xs[rbase + i][kk];   // broadcast reads
            float wv[CPT];
            if constexpr (CPT % 4 == 0) {
#pragma unroll
                for (int j4 = 0; j4 < CPT / 4; ++j4) {
                    float4 w4 = *reinterpret_cast<const float4*>(&wl[kk][cbase + j4 * 4]);
                    wv[j4 * 4 + 0] = w4.x; wv[j4 * 4 + 1] = w4.y;
                    wv[j4 * 4 + 2] = w4.z; wv[j4 * 4 + 3] = w4.w;
                }
            } else {
#pragma unroll
                for (int j = 0; j < CPT; ++j) wv[j] = wl[kk][cbase + j];
            }
#pragma unroll
            for (int i = 0; i < RPT; ++i)
#pragma unroll
                for (int j = 0; j < CPT; ++j)
                    acc[i][j] = fmaf(xv[i], wv[j], acc[i][j]);
        }
    }

    // epilogue: each thread's CPT cols are entirely in Y1 or entirely in Y2
#pragma unroll
    for (int i = 0; i < RPT; ++i) {
        int r = r0 + rbase + i;
        if (r >= N) continue;
        if (cbase < C1) {
#pragma unroll
            for (int j = 0; j < CPT; ++j)
                Y1[(size_t)r * C1 + cbase + j] = acc[i][j];
        } else {
#pragma unroll
            for (int j = 0; j < CPT; ++j)
                Y2[(size_t)r * C2 + (cbase - C1) + j] = acc[i][j] + bs[j];
        }
    }
}

// ---------------- pull aggregation:  Y[node] = relu(Y[node] + sum_e norm * H[srow]) ----------------

template<int C>
__launch_bounds__(256)
__global__ void pull_kernel(const int* __restrict__ offsets,
                            const int* __restrict__ srow,
                            const float* __restrict__ dinv,
                            const float* __restrict__ H,
                            float* __restrict__ Y, int N) {
    constexpr int TPE = C / 4;
    int gid = blockIdx.x * blockDim.x + threadIdx.x;
    int node = gid / TPE;
    int lane = gid - node * TPE;
    if (node >= N) return;

    int e0 = offsets[node];
    int e1 = offsets[node + 1];
    float dc = dinv[node];

    const float4* H4 = reinterpret_cast<const float4*>(H);
    float4 acc = make_float4(0.f, 0.f, 0.f, 0.f);
    for (int j = e0; j < e1; ++j) {
        int r = srow[j];
        float nv = dc * dinv[r];
        float4 hv = H4[(size_t)r * TPE + lane];
        acc.x = fmaf(nv, hv.x, acc.x);
        acc.y = fmaf(nv, hv.y, acc.y);
        acc.z = fmaf(nv, hv.z, acc.z);
        acc.w = fmaf(nv, hv.w, acc.w);
    }

    float4* Y4 = reinterpret_cast<float4*>(Y);
    size_t yi = (size_t)node * TPE + lane;
    float4 y = Y4[yi];
    y.x = fmaxf(y.x + acc.x, 0.f);
    y.y = fmaxf(y.y + acc.y, 0.f);
    y.z = fmaxf(y.z + acc.z, 0.f);
    y.w = fmaxf(y.w + acc.w, 0.f);
    Y4[yi] = y;
}

// ---------------- launcher ----------------

extern "C" void kernel_launch(void* const* d_in, const int* in_sizes, int n_in,
                              void* d_out, int out_size, void* d_ws, size_t ws_size,
                              hipStream_t stream) {
    const float* x       = (const float*)d_in[0];
    const int*   eidx    = (const int*)d_in[1];
    const float* w1_init = (const float*)d_in[2];
    const float* w1_root = (const float*)d_in[3];
    const float* b1      = (const float*)d_in[4];
    const float* w2_init = (const float*)d_in[5];
    const float* w2_root = (const float*)d_in[6];
    const float* b2      = (const float*)d_in[7];
    float* out = (float*)d_out;

    const int* rows = eidx;                // edge_index[0] (source)
    const int* cols = eidx + N_EDGES;      // edge_index[1] (target)

    // workspace layout (4-byte units)
    int* wsi = (int*)d_ws;
    int*   gcount  = wsi;                       //     784
    int*   boff    = wsi + 784;                 //     788 (NBUCK+1 = 783 used)
    int*   gcursor = wsi + 1572;                //     788
    float* dinv    = (float*)(wsi + 2360);      // 100,000
    int*   offsets = wsi + 102360;              // 100,004 (N_NODES+1 used)
    int*   srow    = wsi + 202364;              // 1,000,000
    float* h0      = (float*)(wsi + 1202364);   // 6,400,000  (reused as h2)
    int*   pedge   = wsi + 1202364;             // aliases h0: dead before gemm L1 runs
    float* agg1    = (float*)(wsi + 7602364);   // 6,400,000
    float* h2      = h0;
    // total 14,002,364 * 4 B = 56.0 MB

    // ---- graph prep: bucket partition -> sorted CSR + dinv (no global per-edge atomics) ----
    hipMemsetAsync(gcount, 0, 784 * sizeof(int), stream);
    bucket_count_kernel<<<128, 256, 0, stream>>>(cols, gcount, N_EDGES);
    scan_bucket_kernel<<<1, 1024, 0, stream>>>(gcount, boff, gcursor, offsets);
    bucket_scatter_kernel<<<128, 256, 0, stream>>>(rows, cols, gcursor, pedge, N_EDGES);
    bucket_sort_kernel<<<NBUCK, 256, 0, stream>>>(boff, pedge, srow, offsets, dinv);

    const int GGRID = cdiv(N_NODES, 64);   // 1563

    // ---- layer 1 ----
    gemm_fused_kernel<IN_CH, HID_CH, HID_CH><<<GGRID, 256, 0, stream>>>(
        x, w1_init, w1_root, b1, h0, agg1, N_NODES);
    pull_kernel<HID_CH><<<cdiv(N_NODES * (HID_CH / 4), 256), 256, 0, stream>>>(
        offsets, srow, dinv, h0, agg1, N_NODES);

    // ---- layer 2 ----
    gemm_fused_kernel<HID_CH, N_CLS, N_CLS><<<GGRID, 256, 0, stream>>>(
        agg1, w2_init, w2_root, b2, h2, out, N_NODES);
    pull_kernel<N_CLS><<<cdiv(N_NODES * (N_CLS / 4), 256), 256, 0, stream>>>(
        offsets, srow, dinv, h2, out, N_NODES);
}

// Round 8
// 316.013 us; speedup vs baseline: 3.8419x; 1.0303x over previous
//
#include <hip/hip_runtime.h>

#define N_NODES 100000
#define N_EDGES 1000000
#define IN_CH 128
#define HID_CH 64
#define N_CLS 40

#define NBUCK 782              // ceil(100000 / 128) buckets of 128 target cols

static inline int cdiv(int a, int b) { return (a + b - 1) / b; }

// RNE float->bf16 pack (a in low 16, b in high 16)
__device__ __forceinline__ unsigned pack_bf2(float a, float b) {
    unsigned ua = __float_as_uint(a), ub = __float_as_uint(b);
    ua += 0x7fffu + ((ua >> 16) & 1u);
    ub += 0x7fffu + ((ub >> 16) & 1u);
    return (ua >> 16) | (ub & 0xffff0000u);
}

// ---------------- bucket partition (col >> 7), pass 1: counts ----------------

__global__ __launch_bounds__(256)
void bucket_count_kernel(const int* __restrict__ cols, int* __restrict__ gcount, int E) {
    __shared__ int hist[NBUCK];
    for (int i = threadIdx.x; i < NBUCK; i += 256) hist[i] = 0;
    __syncthreads();
    int per = (E + gridDim.x - 1) / gridDim.x;
    int s = blockIdx.x * per;
    int e = min(E, s + per);
    for (int j = s + threadIdx.x; j < e; j += 256)
        atomicAdd(&hist[cols[j] >> 7], 1);
    __syncthreads();
    for (int i = threadIdx.x; i < NBUCK; i += 256)
        if (hist[i]) atomicAdd(&gcount[i], hist[i]);
}

// ---------------- scan 782 bucket counts -> boff[NBUCK+1], gcursor; offsets[N]=E ----------------

__global__ __launch_bounds__(1024)
void scan_bucket_kernel(const int* __restrict__ gcount, int* __restrict__ boff,
                        int* __restrict__ gcursor, int* __restrict__ offsets) {
    __shared__ int part[1024];
    int t = threadIdx.x;
    part[t] = (t < NBUCK) ? gcount[t] : 0;
    __syncthreads();
    for (int off = 1; off < 1024; off <<= 1) {
        int v = (t >= off) ? part[t - off] : 0;
        __syncthreads();
        part[t] += v;
        __syncthreads();
    }
    int excl = (t > 0) ? part[t - 1] : 0;
    if (t < NBUCK) { boff[t] = excl; gcursor[t] = excl; }
    if (t == NBUCK) { boff[NBUCK] = excl; offsets[N_NODES] = excl; }
}

// ---------------- pass 2: scatter edges into bucket order, packed (row<<7 | col&127) ----------------

__global__ __launch_bounds__(256)
void bucket_scatter_kernel(const int* __restrict__ rows, const int* __restrict__ cols,
                           int* __restrict__ gcursor, int* __restrict__ pedge, int E) {
    __shared__ int cur[NBUCK];
    for (int i = threadIdx.x; i < NBUCK; i += 256) cur[i] = 0;
    __syncthreads();
    int per = (E + gridDim.x - 1) / gridDim.x;
    int s = blockIdx.x * per;
    int e = min(E, s + per);
    for (int j = s + threadIdx.x; j < e; j += 256)
        atomicAdd(&cur[cols[j] >> 7], 1);
    __syncthreads();
    for (int i = threadIdx.x; i < NBUCK; i += 256) {
        int h = cur[i];
        cur[i] = h ? atomicAdd(&gcursor[i], h) : 0;
    }
    __syncthreads();
    for (int j = s + threadIdx.x; j < e; j += 256) {
        int c = cols[j];
        int pos = atomicAdd(&cur[c >> 7], 1);     // LDS returning atomic
        pedge[pos] = (rows[j] << 7) | (c & 127);
    }
}

// ---------------- per-bucket counting sort -> srow (CSR), offsets, dinv ----------------

__global__ __launch_bounds__(256)
void bucket_sort_kernel(const int* __restrict__ boff, const int* __restrict__ pedge,
                        int* __restrict__ srow, int* __restrict__ offsets,
                        float* __restrict__ dinv) {
    __shared__ int cnt[128];
    __shared__ int scn[128];
    __shared__ int cur[128];
    int b = blockIdx.x, t = threadIdx.x;
    if (t < 128) cnt[t] = 0;
    __syncthreads();
    int e0 = boff[b], e1 = boff[b + 1];
    for (int j = e0 + t; j < e1; j += 256)
        atomicAdd(&cnt[pedge[j] & 127], 1);
    __syncthreads();
    if (t < 128) scn[t] = cnt[t];
    __syncthreads();
    for (int off = 1; off < 128; off <<= 1) {
        int v = 0;
        if (t < 128 && t >= off) v = scn[t - off];
        __syncthreads();
        if (t < 128) scn[t] += v;
        __syncthreads();
    }
    if (t < 128) {
        int excl = (t > 0) ? scn[t - 1] : 0;
        cur[t] = excl;
        int node = b * 128 + t;
        if (node < N_NODES) {
            offsets[node] = e0 + excl;
            dinv[node] = cnt[t] ? rsqrtf((float)cnt[t]) : 0.f;
        }
    }
    __syncthreads();
    for (int j = e0 + t; j < e1; j += 256) {
        int p = pedge[j];
        int pos = atomicAdd(&cur[p & 127], 1);
        srow[e0 + pos] = p >> 7;
    }
}

// ---------------- fused GEMM:  Y1b = bf16(X@W1) ; Y2 = X@W2 + Bias ----------------
// 64-row x CT-col tile per 256-thread block; 16x16 thread grid, RPT=4 rows.
// Column remap (round-7 lesson): thread tcol owns cols {tcol*4..+3} (group A)
// and {64 + tcol*CB ..} (group B) -> all wl b128/scalar reads land 2-way or
// conflict-free. Y1 (init path, pull-gather input) stored as packed bf16.

template<int K, int C1, int C2>
__launch_bounds__(256, 4)
__global__ void gemm_fused_kernel(const float* __restrict__ X,
                                  const float* __restrict__ W1,
                                  const float* __restrict__ W2,
                                  const float* __restrict__ Bias,
                                  unsigned* __restrict__ Y1b,   // bf16-packed [N][C1]
                                  float* __restrict__ Y2, int N) {
    constexpr int CT = C1 + C2;
    constexpr int CB = (CT - 64) / 16;     // 4 for CT=128, 1 for CT=80
    constexpr int RPT = 4;
    constexpr int KC = 32;
    constexpr int NCHUNK = K / KC;
    static_assert(CT == 128 || CT == 80, "layout");
    static_assert(C1 % 4 == 0 && C2 % 4 == 0, "vec4");

    __shared__ float wl[KC][CT];           // weight chunk, row-major
    __shared__ float xs[64][KC + 4];       // row-major x tile (stride 36: 2-way reads, free)

    const int tid = threadIdx.x;
    const int r0 = blockIdx.x * 64;
    const int tcol = tid & 15;
    const int trow = tid >> 4;
    const int ca = tcol * 4;               // group A cols: ca..ca+3
    const int cb = 64 + tcol * CB;         // group B cols (always >= C1 -> Y2)
    const int rbase = trow * RPT;

    float bsA[4];
#pragma unroll
    for (int j = 0; j < 4; ++j)
        bsA[j] = (ca >= C1) ? Bias[ca - C1 + j] : 0.f;
    float bsB[CB];
#pragma unroll
    for (int j = 0; j < CB; ++j)
        bsB[j] = Bias[cb - C1 + j];

    float accA[RPT][4];
    float accB[RPT][CB];
#pragma unroll
    for (int i = 0; i < RPT; ++i) {
#pragma unroll
        for (int j = 0; j < 4; ++j) accA[i][j] = 0.f;
#pragma unroll
        for (int j = 0; j < CB; ++j) accB[i][j] = 0.f;
    }

    for (int ch = 0; ch < NCHUNK; ++ch) {
        __syncthreads();
        constexpr int W1F4 = KC * C1 / 4;
        constexpr int W2F4 = KC * C2 / 4;
        for (int i = tid; i < W1F4; i += 256) {
            int kk = i / (C1 / 4);
            int f4 = i - kk * (C1 / 4);
            float4 v = *reinterpret_cast<const float4*>(&W1[(size_t)(ch * KC + kk) * C1 + f4 * 4]);
            *reinterpret_cast<float4*>(&wl[kk][f4 * 4]) = v;
        }
        for (int i = tid; i < W2F4; i += 256) {
            int kk = i / (C2 / 4);
            int f4 = i - kk * (C2 / 4);
            float4 v = *reinterpret_cast<const float4*>(&W2[(size_t)(ch * KC + kk) * C2 + f4 * 4]);
            *reinterpret_cast<float4*>(&wl[kk][C1 + f4 * 4]) = v;
        }
        constexpr int XF4 = 64 * KC / 4;
        for (int i = tid; i < XF4; i += 256) {
            int rr = i / (KC / 4);
            int k4 = i - rr * (KC / 4);
            int gr = r0 + rr;
            float4 v = make_float4(0.f, 0.f, 0.f, 0.f);
            if (gr < N)
                v = *reinterpret_cast<const float4*>(&X[(size_t)gr * K + ch * KC + k4 * 4]);
            *reinterpret_cast<float4*>(&xs[rr][k4 * 4]) = v;
        }
        __syncthreads();
#pragma unroll 8
        for (int kk = 0; kk < KC; ++kk) {
            float xv[RPT];
#pragma unroll
            for (int i = 0; i < RPT; ++i) xv[i] = xs[rbase + i][kk];
            float4 wA = *reinterpret_cast<const float4*>(&wl[kk][ca]);
            float wB[CB];
            if constexpr (CB == 4) {
                float4 w4 = *reinterpret_cast<const float4*>(&wl[kk][cb]);
                wB[0] = w4.x; wB[1] = w4.y; wB[2] = w4.z; wB[3] = w4.w;
            } else {
                wB[0] = wl[kk][cb];
            }
#pragma unroll
            for (int i = 0; i < RPT; ++i) {
                accA[i][0] = fmaf(xv[i], wA.x, accA[i][0]);
                accA[i][1] = fmaf(xv[i], wA.y, accA[i][1]);
                accA[i][2] = fmaf(xv[i], wA.z, accA[i][2]);
                accA[i][3] = fmaf(xv[i], wA.w, accA[i][3]);
#pragma unroll
                for (int j = 0; j < CB; ++j)
                    accB[i][j] = fmaf(xv[i], wB[j], accB[i][j]);
            }
        }
    }

#pragma unroll
    for (int i = 0; i < RPT; ++i) {
        int r = r0 + rbase + i;
        if (r >= N) continue;
        // group A: entirely Y1 (bf16) or entirely Y2 (boundary C1 is a multiple of 4)
        if (ca < C1) {
            uint2 p;
            p.x = pack_bf2(accA[i][0], accA[i][1]);
            p.y = pack_bf2(accA[i][2], accA[i][3]);
            *reinterpret_cast<uint2*>(&Y1b[((size_t)r * C1 + ca) >> 1]) = p;
        } else {
            float4 v = make_float4(accA[i][0] + bsA[0], accA[i][1] + bsA[1],
                                   accA[i][2] + bsA[2], accA[i][3] + bsA[3]);
            *reinterpret_cast<float4*>(&Y2[(size_t)r * C2 + (ca - C1)]) = v;
        }
        // group B: always Y2
        if constexpr (CB == 4) {
            float4 v = make_float4(accB[i][0] + bsB[0], accB[i][1] + bsB[1],
                                   accB[i][2] + bsB[2], accB[i][3] + bsB[3]);
            *reinterpret_cast<float4*>(&Y2[(size_t)r * C2 + (cb - C1)]) = v;
        } else {
            Y2[(size_t)r * C2 + (cb - C1)] = accB[i][0] + bsB[0];
        }
    }
}

// ---------------- pull aggregation over bf16 H:  Y = relu(Y + sum norm * H[srow]) ----------------

template<int C>
__launch_bounds__(256)
__global__ void pull_bf16_kernel(const int* __restrict__ offsets,
                                 const int* __restrict__ srow,
                                 const float* __restrict__ dinv,
                                 const unsigned* __restrict__ H,   // bf16-packed [N][C]
                                 float* __restrict__ Y, int N) {
    constexpr int TPE = C / 4;             // lanes per node, 4 bf16 (uint2) each
    int gid = blockIdx.x * blockDim.x + threadIdx.x;
    int node = gid / TPE;
    int lane = gid - node * TPE;
    if (node >= N) return;

    int e0 = offsets[node];
    int e1 = offsets[node + 1];
    float dc = dinv[node];

    float4 acc = make_float4(0.f, 0.f, 0.f, 0.f);
    for (int j = e0; j < e1; ++j) {
        int r = srow[j];
        float nv = dc * dinv[r];
        uint2 u = *reinterpret_cast<const uint2*>(&H[(size_t)r * (C / 2) + lane * 2]);
        float f0 = __uint_as_float(u.x << 16);
        float f1 = __uint_as_float(u.x & 0xffff0000u);
        float f2 = __uint_as_float(u.y << 16);
        float f3 = __uint_as_float(u.y & 0xffff0000u);
        acc.x = fmaf(nv, f0, acc.x);
        acc.y = fmaf(nv, f1, acc.y);
        acc.z = fmaf(nv, f2, acc.z);
        acc.w = fmaf(nv, f3, acc.w);
    }

    float4* Y4 = reinterpret_cast<float4*>(Y);
    size_t yi = (size_t)node * TPE + lane;
    float4 y = Y4[yi];
    y.x = fmaxf(y.x + acc.x, 0.f);
    y.y = fmaxf(y.y + acc.y, 0.f);
    y.z = fmaxf(y.z + acc.z, 0.f);
    y.w = fmaxf(y.w + acc.w, 0.f);
    Y4[yi] = y;
}

// ---------------- launcher ----------------

extern "C" void kernel_launch(void* const* d_in, const int* in_sizes, int n_in,
                              void* d_out, int out_size, void* d_ws, size_t ws_size,
                              hipStream_t stream) {
    const float* x       = (const float*)d_in[0];
    const int*   eidx    = (const int*)d_in[1];
    const float* w1_init = (const float*)d_in[2];
    const float* w1_root = (const float*)d_in[3];
    const float* b1      = (const float*)d_in[4];
    const float* w2_init = (const float*)d_in[5];
    const float* w2_root = (const float*)d_in[6];
    const float* b2      = (const float*)d_in[7];
    float* out = (float*)d_out;

    const int* rows = eidx;                // edge_index[0] (source)
    const int* cols = eidx + N_EDGES;      // edge_index[1] (target)

    // workspace layout (4-byte units)
    int* wsi = (int*)d_ws;
    int*      gcount  = wsi;                         //     784
    int*      boff    = wsi + 784;                   //     788 (NBUCK+1 = 783 used)
    int*      gcursor = wsi + 1572;                  //     788
    float*    dinv    = (float*)(wsi + 2360);        //   100,000
    int*      offsets = wsi + 102360;                //   100,004 (N_NODES+1 used)
    int*      srow    = wsi + 202364;                // 1,000,000
    unsigned* h0b     = (unsigned*)(wsi + 1202364);  // 3,200,000 uints (bf16 h, reused as h2b)
    int*      pedge   = wsi + 1202364;               // aliases h0b: dead before gemm L1
    float*    agg1    = (float*)(wsi + 4402364);     // 6,400,000
    unsigned* h2b     = h0b;
    // total 10,802,364 * 4 B = 43.2 MB

    // ---- graph prep: bucket partition -> sorted CSR + dinv (no global per-edge atomics) ----
    hipMemsetAsync(gcount, 0, 784 * sizeof(int), stream);
    bucket_count_kernel<<<128, 256, 0, stream>>>(cols, gcount, N_EDGES);
    scan_bucket_kernel<<<1, 1024, 0, stream>>>(gcount, boff, gcursor, offsets);
    bucket_scatter_kernel<<<128, 256, 0, stream>>>(rows, cols, gcursor, pedge, N_EDGES);
    bucket_sort_kernel<<<NBUCK, 256, 0, stream>>>(boff, pedge, srow, offsets, dinv);

    const int GGRID = cdiv(N_NODES, 64);   // 1563

    // ---- layer 1 ----
    gemm_fused_kernel<IN_CH, HID_CH, HID_CH><<<GGRID, 256, 0, stream>>>(
        x, w1_init, w1_root, b1, h0b, agg1, N_NODES);
    pull_bf16_kernel<HID_CH><<<cdiv(N_NODES * (HID_CH / 4), 256), 256, 0, stream>>>(
        offsets, srow, dinv, h0b, agg1, N_NODES);

    // ---- layer 2 ----
    gemm_fused_kernel<HID_CH, N_CLS, N_CLS><<<GGRID, 256, 0, stream>>>(
        agg1, w2_init, w2_root, b2, h2b, out, N_NODES);
    pull_bf16_kernel<N_CLS><<<cdiv(N_NODES * (N_CLS / 4), 256), 256, 0, stream>>>(
        offsets, srow, dinv, h2b, out, N_NODES);
}

// Round 9
// 287.488 us; speedup vs baseline: 4.2231x; 1.0992x over previous
//
#include <hip/hip_runtime.h>

#define N_NODES 100000
#define N_EDGES 1000000
#define IN_CH 128
#define HID_CH 64
#define N_CLS 40

#define NBUCK 782              // ceil(100000 / 128) buckets of 128 target cols

static inline int cdiv(int a, int b) { return (a + b - 1) / b; }

// RNE float->bf16 pack (a in low 16, b in high 16)
__device__ __forceinline__ unsigned pack_bf2(float a, float b) {
    unsigned ua = __float_as_uint(a), ub = __float_as_uint(b);
    ua += 0x7fffu + ((ua >> 16) & 1u);
    ub += 0x7fffu + ((ub >> 16) & 1u);
    return (ua >> 16) | (ub & 0xffff0000u);
}
__device__ __forceinline__ float bf_lo(unsigned u) { return __uint_as_float(u << 16); }
__device__ __forceinline__ float bf_hi(unsigned u) { return __uint_as_float(u & 0xffff0000u); }

// ---------------- bucket partition (col >> 7), pass 1: counts ----------------

__global__ __launch_bounds__(256)
void bucket_count_kernel(const int* __restrict__ cols, int* __restrict__ gcount, int E) {
    __shared__ int hist[NBUCK];
    for (int i = threadIdx.x; i < NBUCK; i += 256) hist[i] = 0;
    __syncthreads();
    int per = (E + gridDim.x - 1) / gridDim.x;
    int s = blockIdx.x * per;
    int e = min(E, s + per);
    for (int j = s + threadIdx.x; j < e; j += 256)
        atomicAdd(&hist[cols[j] >> 7], 1);
    __syncthreads();
    for (int i = threadIdx.x; i < NBUCK; i += 256)
        if (hist[i]) atomicAdd(&gcount[i], hist[i]);
}

// ---------------- scan 782 bucket counts -> boff[NBUCK+1], gcursor; offsets[N]=E ----------------

__global__ __launch_bounds__(1024)
void scan_bucket_kernel(const int* __restrict__ gcount, int* __restrict__ boff,
                        int* __restrict__ gcursor, int* __restrict__ offsets) {
    __shared__ int part[1024];
    int t = threadIdx.x;
    part[t] = (t < NBUCK) ? gcount[t] : 0;
    __syncthreads();
    for (int off = 1; off < 1024; off <<= 1) {
        int v = (t >= off) ? part[t - off] : 0;
        __syncthreads();
        part[t] += v;
        __syncthreads();
    }
    int excl = (t > 0) ? part[t - 1] : 0;
    if (t < NBUCK) { boff[t] = excl; gcursor[t] = excl; }
    if (t == NBUCK) { boff[NBUCK] = excl; offsets[N_NODES] = excl; }
}

// ---------------- pass 2: scatter edges into bucket order, packed (row<<7 | col&127) ----------------

__global__ __launch_bounds__(256)
void bucket_scatter_kernel(const int* __restrict__ rows, const int* __restrict__ cols,
                           int* __restrict__ gcursor, int* __restrict__ pedge, int E) {
    __shared__ int cur[NBUCK];
    for (int i = threadIdx.x; i < NBUCK; i += 256) cur[i] = 0;
    __syncthreads();
    int per = (E + gridDim.x - 1) / gridDim.x;
    int s = blockIdx.x * per;
    int e = min(E, s + per);
    for (int j = s + threadIdx.x; j < e; j += 256)
        atomicAdd(&cur[cols[j] >> 7], 1);
    __syncthreads();
    for (int i = threadIdx.x; i < NBUCK; i += 256) {
        int h = cur[i];
        cur[i] = h ? atomicAdd(&gcursor[i], h) : 0;
    }
    __syncthreads();
    for (int j = s + threadIdx.x; j < e; j += 256) {
        int c = cols[j];
        int pos = atomicAdd(&cur[c >> 7], 1);     // LDS returning atomic
        pedge[pos] = (rows[j] << 7) | (c & 127);
    }
}

// ---------------- per-bucket counting sort -> srow (CSR), offsets, dinv ----------------

__global__ __launch_bounds__(256)
void bucket_sort_kernel(const int* __restrict__ boff, const int* __restrict__ pedge,
                        int* __restrict__ srow, int* __restrict__ offsets,
                        float* __restrict__ dinv) {
    __shared__ int cnt[128];
    __shared__ int scn[128];
    __shared__ int cur[128];
    int b = blockIdx.x, t = threadIdx.x;
    if (t < 128) cnt[t] = 0;
    __syncthreads();
    int e0 = boff[b], e1 = boff[b + 1];
    for (int j = e0 + t; j < e1; j += 256)
        atomicAdd(&cnt[pedge[j] & 127], 1);
    __syncthreads();
    if (t < 128) scn[t] = cnt[t];
    __syncthreads();
    for (int off = 1; off < 128; off <<= 1) {
        int v = 0;
        if (t < 128 && t >= off) v = scn[t - off];
        __syncthreads();
        if (t < 128) scn[t] += v;
        __syncthreads();
    }
    if (t < 128) {
        int excl = (t > 0) ? scn[t - 1] : 0;
        cur[t] = excl;
        int node = b * 128 + t;
        if (node < N_NODES) {
            offsets[node] = e0 + excl;
            dinv[node] = cnt[t] ? rsqrtf((float)cnt[t]) : 0.f;
        }
    }
    __syncthreads();
    for (int j = e0 + t; j < e1; j += 256) {
        int p = pedge[j];
        int pos = atomicAdd(&cur[p & 127], 1);
        srow[e0 + pos] = p >> 7;
    }
}

// ---------------- fused GEMM:  Y1b = bf16(dinv[r] * (X@W1)) ; Y2 = X@W2 + Bias ----------------
// 64-row x CT-col tile per 256-thread block; 16x16 thread grid, RPT=4 rows.
// Column remap: thread tcol owns cols {tcol*4..+3} (group A) and {64+tcol*CB..}
// (group B) -> all wl reads conflict-free (round-7/8 lesson). Y1 (init path,
// pull-gather input) stored bf16 PRE-SCALED by dinv[row] so the pull loop has
// no dinv gather (round-8 lesson: pull is latency-bound, shorten the chain).

template<int K, int C1, int C2>
__launch_bounds__(256, 4)
__global__ void gemm_fused_kernel(const float* __restrict__ X,
                                  const float* __restrict__ W1,
                                  const float* __restrict__ W2,
                                  const float* __restrict__ Bias,
                                  const float* __restrict__ dinv,
                                  unsigned* __restrict__ Y1b,   // bf16-packed [N][C1]
                                  float* __restrict__ Y2, int N) {
    constexpr int CT = C1 + C2;
    constexpr int CB = (CT - 64) / 16;     // 4 for CT=128, 1 for CT=80
    constexpr int RPT = 4;
    constexpr int KC = 32;
    constexpr int NCHUNK = K / KC;
    static_assert(CT == 128 || CT == 80, "layout");
    static_assert(C1 % 4 == 0 && C2 % 4 == 0, "vec4");

    __shared__ float wl[KC][CT];           // weight chunk, row-major
    __shared__ float xs[64][KC + 4];       // row-major x tile

    const int tid = threadIdx.x;
    const int r0 = blockIdx.x * 64;
    const int tcol = tid & 15;
    const int trow = tid >> 4;
    const int ca = tcol * 4;               // group A cols: ca..ca+3
    const int cb = 64 + tcol * CB;         // group B cols (always >= C1 -> Y2)
    const int rbase = trow * RPT;

    float bsA[4];
#pragma unroll
    for (int j = 0; j < 4; ++j)
        bsA[j] = (ca >= C1) ? Bias[ca - C1 + j] : 0.f;
    float bsB[CB];
#pragma unroll
    for (int j = 0; j < CB; ++j)
        bsB[j] = Bias[cb - C1 + j];

    float accA[RPT][4];
    float accB[RPT][CB];
#pragma unroll
    for (int i = 0; i < RPT; ++i) {
#pragma unroll
        for (int j = 0; j < 4; ++j) accA[i][j] = 0.f;
#pragma unroll
        for (int j = 0; j < CB; ++j) accB[i][j] = 0.f;
    }

    for (int ch = 0; ch < NCHUNK; ++ch) {
        __syncthreads();
        constexpr int W1F4 = KC * C1 / 4;
        constexpr int W2F4 = KC * C2 / 4;
        for (int i = tid; i < W1F4; i += 256) {
            int kk = i / (C1 / 4);
            int f4 = i - kk * (C1 / 4);
            float4 v = *reinterpret_cast<const float4*>(&W1[(size_t)(ch * KC + kk) * C1 + f4 * 4]);
            *reinterpret_cast<float4*>(&wl[kk][f4 * 4]) = v;
        }
        for (int i = tid; i < W2F4; i += 256) {
            int kk = i / (C2 / 4);
            int f4 = i - kk * (C2 / 4);
            float4 v = *reinterpret_cast<const float4*>(&W2[(size_t)(ch * KC + kk) * C2 + f4 * 4]);
            *reinterpret_cast<float4*>(&wl[kk][C1 + f4 * 4]) = v;
        }
        constexpr int XF4 = 64 * KC / 4;
        for (int i = tid; i < XF4; i += 256) {
            int rr = i / (KC / 4);
            int k4 = i - rr * (KC / 4);
            int gr = r0 + rr;
            float4 v = make_float4(0.f, 0.f, 0.f, 0.f);
            if (gr < N)
                v = *reinterpret_cast<const float4*>(&X[(size_t)gr * K + ch * KC + k4 * 4]);
            *reinterpret_cast<float4*>(&xs[rr][k4 * 4]) = v;
        }
        __syncthreads();
#pragma unroll 8
        for (int kk = 0; kk < KC; ++kk) {
            float xv[RPT];
#pragma unroll
            for (int i = 0; i < RPT; ++i) xv[i] = xs[rbase + i][kk];
            float4 wA = *reinterpret_cast<const float4*>(&wl[kk][ca]);
            float wB[CB];
            if constexpr (CB == 4) {
                float4 w4 = *reinterpret_cast<const float4*>(&wl[kk][cb]);
                wB[0] = w4.x; wB[1] = w4.y; wB[2] = w4.z; wB[3] = w4.w;
            } else {
                wB[0] = wl[kk][cb];
            }
#pragma unroll
            for (int i = 0; i < RPT; ++i) {
                accA[i][0] = fmaf(xv[i], wA.x, accA[i][0]);
                accA[i][1] = fmaf(xv[i], wA.y, accA[i][1]);
                accA[i][2] = fmaf(xv[i], wA.z, accA[i][2]);
                accA[i][3] = fmaf(xv[i], wA.w, accA[i][3]);
#pragma unroll
                for (int j = 0; j < CB; ++j)
                    accB[i][j] = fmaf(xv[i], wB[j], accB[i][j]);
            }
        }
    }

#pragma unroll
    for (int i = 0; i < RPT; ++i) {
        int r = r0 + rbase + i;
        if (r >= N) continue;
        // group A: entirely Y1 (bf16, pre-scaled by dinv) or entirely Y2
        if (ca < C1) {
            float dr = dinv[r];
            uint2 p;
            p.x = pack_bf2(accA[i][0] * dr, accA[i][1] * dr);
            p.y = pack_bf2(accA[i][2] * dr, accA[i][3] * dr);
            *reinterpret_cast<uint2*>(&Y1b[((size_t)r * C1 + ca) >> 1]) = p;
        } else {
            float4 v = make_float4(accA[i][0] + bsA[0], accA[i][1] + bsA[1],
                                   accA[i][2] + bsA[2], accA[i][3] + bsA[3]);
            *reinterpret_cast<float4*>(&Y2[(size_t)r * C2 + (ca - C1)]) = v;
        }
        // group B: always Y2
        if constexpr (CB == 4) {
            float4 v = make_float4(accB[i][0] + bsB[0], accB[i][1] + bsB[1],
                                   accB[i][2] + bsB[2], accB[i][3] + bsB[3]);
            *reinterpret_cast<float4*>(&Y2[(size_t)r * C2 + (cb - C1)]) = v;
        } else {
            Y2[(size_t)r * C2 + (cb - C1)] = accB[i][0] + bsB[0];
        }
    }
}

// ---------------- pull aggregation over pre-scaled bf16 H ----------------
//  Y[node] = relu(Y[node] + dinv[node] * sum_e H[srow[e]])
// Edge loop unrolled x4: 4 independent srow loads -> 4 independent H gathers
// in flight (MLP=4; round-8 lesson: this loop is latency-bound, not BW-bound).

template<int C>
__launch_bounds__(256)
__global__ void pull_bf16_kernel(const int* __restrict__ offsets,
                                 const int* __restrict__ srow,
                                 const float* __restrict__ dinv,
                                 const unsigned* __restrict__ H,   // bf16 [N][C], pre-scaled
                                 float* __restrict__ Y, int N) {
    constexpr int TPE = C / 4;             // lanes per node, 4 bf16 (uint2) each
    constexpr int CH = C / 2;              // uints per row
    int gid = blockIdx.x * blockDim.x + threadIdx.x;
    int node = gid / TPE;
    int lane = gid - node * TPE;
    if (node >= N) return;

    int e0 = offsets[node];
    int e1 = offsets[node + 1];
    float dc = dinv[node];

    float4 acc = make_float4(0.f, 0.f, 0.f, 0.f);
    int j = e0;
    for (; j + 4 <= e1; j += 4) {
        int r0 = srow[j + 0];
        int r1 = srow[j + 1];
        int r2 = srow[j + 2];
        int r3 = srow[j + 3];
        uint2 u0 = *reinterpret_cast<const uint2*>(&H[(size_t)r0 * CH + lane * 2]);
        uint2 u1 = *reinterpret_cast<const uint2*>(&H[(size_t)r1 * CH + lane * 2]);
        uint2 u2 = *reinterpret_cast<const uint2*>(&H[(size_t)r2 * CH + lane * 2]);
        uint2 u3 = *reinterpret_cast<const uint2*>(&H[(size_t)r3 * CH + lane * 2]);
        acc.x += (bf_lo(u0.x) + bf_lo(u1.x)) + (bf_lo(u2.x) + bf_lo(u3.x));
        acc.y += (bf_hi(u0.x) + bf_hi(u1.x)) + (bf_hi(u2.x) + bf_hi(u3.x));
        acc.z += (bf_lo(u0.y) + bf_lo(u1.y)) + (bf_lo(u2.y) + bf_lo(u3.y));
        acc.w += (bf_hi(u0.y) + bf_hi(u1.y)) + (bf_hi(u2.y) + bf_hi(u3.y));
    }
    for (; j < e1; ++j) {
        int r = srow[j];
        uint2 u = *reinterpret_cast<const uint2*>(&H[(size_t)r * CH + lane * 2]);
        acc.x += bf_lo(u.x);
        acc.y += bf_hi(u.x);
        acc.z += bf_lo(u.y);
        acc.w += bf_hi(u.y);
    }

    float4* Y4 = reinterpret_cast<float4*>(Y);
    size_t yi = (size_t)node * TPE + lane;
    float4 y = Y4[yi];
    y.x = fmaxf(fmaf(dc, acc.x, y.x), 0.f);
    y.y = fmaxf(fmaf(dc, acc.y, y.y), 0.f);
    y.z = fmaxf(fmaf(dc, acc.z, y.z), 0.f);
    y.w = fmaxf(fmaf(dc, acc.w, y.w), 0.f);
    Y4[yi] = y;
}

// ---------------- launcher ----------------

extern "C" void kernel_launch(void* const* d_in, const int* in_sizes, int n_in,
                              void* d_out, int out_size, void* d_ws, size_t ws_size,
                              hipStream_t stream) {
    const float* x       = (const float*)d_in[0];
    const int*   eidx    = (const int*)d_in[1];
    const float* w1_init = (const float*)d_in[2];
    const float* w1_root = (const float*)d_in[3];
    const float* b1      = (const float*)d_in[4];
    const float* w2_init = (const float*)d_in[5];
    const float* w2_root = (const float*)d_in[6];
    const float* b2      = (const float*)d_in[7];
    float* out = (float*)d_out;

    const int* rows = eidx;                // edge_index[0] (source)
    const int* cols = eidx + N_EDGES;      // edge_index[1] (target)

    // workspace layout (4-byte units)
    int* wsi = (int*)d_ws;
    int*      gcount  = wsi;                         //     784
    int*      boff    = wsi + 784;                   //     788 (NBUCK+1 = 783 used)
    int*      gcursor = wsi + 1572;                  //     788
    float*    dinv    = (float*)(wsi + 2360);        //   100,000
    int*      offsets = wsi + 102360;                //   100,004 (N_NODES+1 used)
    int*      srow    = wsi + 202364;                // 1,000,000
    unsigned* h0b     = (unsigned*)(wsi + 1202364);  // 3,200,000 uints (bf16 h, reused as h2b)
    int*      pedge   = wsi + 1202364;               // aliases h0b: dead before gemm L1
    float*    agg1    = (float*)(wsi + 4402364);     // 6,400,000
    unsigned* h2b     = h0b;
    // total 10,802,364 * 4 B = 43.2 MB

    // ---- graph prep: bucket partition -> sorted CSR + dinv (no global per-edge atomics) ----
    hipMemsetAsync(gcount, 0, 784 * sizeof(int), stream);
    bucket_count_kernel<<<128, 256, 0, stream>>>(cols, gcount, N_EDGES);
    scan_bucket_kernel<<<1, 1024, 0, stream>>>(gcount, boff, gcursor, offsets);
    bucket_scatter_kernel<<<128, 256, 0, stream>>>(rows, cols, gcursor, pedge, N_EDGES);
    bucket_sort_kernel<<<NBUCK, 256, 0, stream>>>(boff, pedge, srow, offsets, dinv);

    const int GGRID = cdiv(N_NODES, 64);   // 1563

    // ---- layer 1 ----
    gemm_fused_kernel<IN_CH, HID_CH, HID_CH><<<GGRID, 256, 0, stream>>>(
        x, w1_init, w1_root, b1, dinv, h0b, agg1, N_NODES);
    pull_bf16_kernel<HID_CH><<<cdiv(N_NODES * (HID_CH / 4), 256), 256, 0, stream>>>(
        offsets, srow, dinv, h0b, agg1, N_NODES);

    // ---- layer 2 ----
    gemm_fused_kernel<HID_CH, N_CLS, N_CLS><<<GGRID, 256, 0, stream>>>(
        agg1, w2_init, w2_root, b2, dinv, h2b, out, N_NODES);
    pull_bf16_kernel<N_CLS><<<cdiv(N_NODES * (N_CLS / 4), 256), 256, 0, stream>>>(
        offsets, srow, dinv, h2b, out, N_NODES);
}

// Round 10
// 264.525 us; speedup vs baseline: 4.5897x; 1.0868x over previous
//
#include <hip/hip_runtime.h>

#define N_NODES 100000
#define N_EDGES 1000000
#define IN_CH 128
#define HID_CH 64
#define N_CLS 40

#define NBUCK 782              // ceil(100000 / 128) buckets of 128 target cols

static inline int cdiv(int a, int b) { return (a + b - 1) / b; }

using bf16x8 = __attribute__((ext_vector_type(8))) short;   // 8 bf16 (4 VGPRs)
using f32x4  = __attribute__((ext_vector_type(4))) float;   // MFMA accumulator

// RNE float->bf16 pack (a in low 16, b in high 16)
__device__ __forceinline__ unsigned pack_bf2(float a, float b) {
    unsigned ua = __float_as_uint(a), ub = __float_as_uint(b);
    ua += 0x7fffu + ((ua >> 16) & 1u);
    ub += 0x7fffu + ((ub >> 16) & 1u);
    return (ua >> 16) | (ub & 0xffff0000u);
}
__device__ __forceinline__ unsigned short bf16_of(float a) {
    unsigned ua = __float_as_uint(a);
    ua += 0x7fffu + ((ua >> 16) & 1u);
    return (unsigned short)(ua >> 16);
}
__device__ __forceinline__ float bf_lo(unsigned u) { return __uint_as_float(u << 16); }
__device__ __forceinline__ float bf_hi(unsigned u) { return __uint_as_float(u & 0xffff0000u); }

// ---------------- bucket partition (col >> 7), pass 1: counts ----------------

__global__ __launch_bounds__(256)
void bucket_count_kernel(const int* __restrict__ cols, int* __restrict__ gcount, int E) {
    __shared__ int hist[NBUCK];
    for (int i = threadIdx.x; i < NBUCK; i += 256) hist[i] = 0;
    __syncthreads();
    int per = (E + gridDim.x - 1) / gridDim.x;
    int s = blockIdx.x * per;
    int e = min(E, s + per);
    for (int j = s + threadIdx.x; j < e; j += 256)
        atomicAdd(&hist[cols[j] >> 7], 1);
    __syncthreads();
    for (int i = threadIdx.x; i < NBUCK; i += 256)
        if (hist[i]) atomicAdd(&gcount[i], hist[i]);
}

// ---------------- scan 782 bucket counts -> boff[NBUCK+1], gcursor; offsets[N]=E ----------------

__global__ __launch_bounds__(1024)
void scan_bucket_kernel(const int* __restrict__ gcount, int* __restrict__ boff,
                        int* __restrict__ gcursor, int* __restrict__ offsets) {
    __shared__ int part[1024];
    int t = threadIdx.x;
    part[t] = (t < NBUCK) ? gcount[t] : 0;
    __syncthreads();
    for (int off = 1; off < 1024; off <<= 1) {
        int v = (t >= off) ? part[t - off] : 0;
        __syncthreads();
        part[t] += v;
        __syncthreads();
    }
    int excl = (t > 0) ? part[t - 1] : 0;
    if (t < NBUCK) { boff[t] = excl; gcursor[t] = excl; }
    if (t == NBUCK) { boff[NBUCK] = excl; offsets[N_NODES] = excl; }
}

// ---------------- pass 2: scatter edges into bucket order, packed (row<<7 | col&127) ----------------

__global__ __launch_bounds__(256)
void bucket_scatter_kernel(const int* __restrict__ rows, const int* __restrict__ cols,
                           int* __restrict__ gcursor, int* __restrict__ pedge, int E) {
    __shared__ int cur[NBUCK];
    for (int i = threadIdx.x; i < NBUCK; i += 256) cur[i] = 0;
    __syncthreads();
    int per = (E + gridDim.x - 1) / gridDim.x;
    int s = blockIdx.x * per;
    int e = min(E, s + per);
    for (int j = s + threadIdx.x; j < e; j += 256)
        atomicAdd(&cur[cols[j] >> 7], 1);
    __syncthreads();
    for (int i = threadIdx.x; i < NBUCK; i += 256) {
        int h = cur[i];
        cur[i] = h ? atomicAdd(&gcursor[i], h) : 0;
    }
    __syncthreads();
    for (int j = s + threadIdx.x; j < e; j += 256) {
        int c = cols[j];
        int pos = atomicAdd(&cur[c >> 7], 1);     // LDS returning atomic
        pedge[pos] = (rows[j] << 7) | (c & 127);
    }
}

// ---------------- per-bucket counting sort -> srow (CSR), offsets, dinv ----------------

__global__ __launch_bounds__(256)
void bucket_sort_kernel(const int* __restrict__ boff, const int* __restrict__ pedge,
                        int* __restrict__ srow, int* __restrict__ offsets,
                        float* __restrict__ dinv) {
    __shared__ int cnt[128];
    __shared__ int scn[128];
    __shared__ int cur[128];
    int b = blockIdx.x, t = threadIdx.x;
    if (t < 128) cnt[t] = 0;
    __syncthreads();
    int e0 = boff[b], e1 = boff[b + 1];
    for (int j = e0 + t; j < e1; j += 256)
        atomicAdd(&cnt[pedge[j] & 127], 1);
    __syncthreads();
    if (t < 128) scn[t] = cnt[t];
    __syncthreads();
    for (int off = 1; off < 128; off <<= 1) {
        int v = 0;
        if (t < 128 && t >= off) v = scn[t - off];
        __syncthreads();
        if (t < 128) scn[t] += v;
        __syncthreads();
    }
    if (t < 128) {
        int excl = (t > 0) ? scn[t - 1] : 0;
        cur[t] = excl;
        int node = b * 128 + t;
        if (node < N_NODES) {
            offsets[node] = e0 + excl;
            dinv[node] = cnt[t] ? rsqrtf((float)cnt[t]) : 0.f;
        }
    }
    __syncthreads();
    for (int j = e0 + t; j < e1; j += 256) {
        int p = pedge[j];
        int pos = atomicAdd(&cur[p & 127], 1);
        srow[e0 + pos] = p >> 7;
    }
}

// ---------------- MFMA fused GEMM ----------------
//  Y1b = bf16(dinv[r] * (X@W1))  (u16 stores, pull-gather input)
//  Y2  = X@W2 + Bias             (f32)
// 64-row tile / block of 256 (4 waves); wave w owns rows w*16..+15.
// X and W cast to bf16 at staging; W staged TRANSPOSED (wt[c][k]) so the
// B-fragment is one b128. Row pad 8 bf16 -> dword stride 68/36 (mod 32 = 4):
// 2-way bank aliasing = free. mfma_f32_16x16x32_bf16, f32 accumulate.
// A-frag: a[j]=A[m][ks*32+q*8+j], m=lane&15, q=lane>>4; C/D: col=lane&15,
// row=q*4+reg (verified maps).

template<int K, int C1, int C2>
__launch_bounds__(256)
__global__ void gemm_mfma_fused_kernel(const float* __restrict__ X,
                                       const float* __restrict__ W1,
                                       const float* __restrict__ W2,
                                       const float* __restrict__ Bias,
                                       const float* __restrict__ dinv,
                                       unsigned short* __restrict__ Y1b, // bf16 [N][C1]
                                       float* __restrict__ Y2, int N) {
    constexpr int CT = C1 + C2;
    constexpr int NT = CT / 16;            // 16-col tiles: 8 (L1) / 5 (L2)
    constexpr int KS = K / 32;             // k-steps: 4 (L1) / 2 (L2)
    constexpr int KP = (K + 8) / 2;        // dwords per padded bf16 row (68 / 36)
    static_assert(CT % 16 == 0 && K % 32 == 0, "shape");
    static_assert(C1 % 4 == 0 && C2 % 4 == 0, "staging vec4");

    __shared__ unsigned xb[64 * KP];       // bf16 x tile [64][K+8]
    __shared__ unsigned wt[CT * KP];       // bf16 W^T    [CT][K+8]
    __shared__ float dloc[64];

    const int tid = threadIdx.x;
    const int wave = tid >> 6;
    const int lane = tid & 63;
    const int m = lane & 15;
    const int quad = lane >> 4;
    const int r0 = blockIdx.x * 64;

    // stage dinv for this block's rows
    if (tid < 64) {
        int gr = r0 + tid;
        dloc[tid] = (gr < N) ? dinv[gr] : 0.f;
    }

    // stage x -> bf16 (row-major, padded)
    constexpr int XIT = 64 * (K / 4);
    for (int i = tid; i < XIT; i += 256) {
        int rr = i / (K / 4);
        int k4 = i - rr * (K / 4);
        int gr = r0 + rr;
        float4 v = make_float4(0.f, 0.f, 0.f, 0.f);
        if (gr < N)
            v = *reinterpret_cast<const float4*>(&X[(size_t)gr * K + k4 * 4]);
        uint2 p;
        p.x = pack_bf2(v.x, v.y);
        p.y = pack_bf2(v.z, v.w);
        *reinterpret_cast<uint2*>(&xb[rr * KP + k4 * 2]) = p;
    }

    // stage W1|W2 -> bf16 transposed: wt[c][k], k-pairs packed per dword
    constexpr int WIT = (K / 2) * (CT / 4);
    for (int i = tid; i < WIT; i += 256) {
        int kp = i / (CT / 4);
        int c4 = i - kp * (CT / 4);
        int k = kp * 2;
        int c = c4 * 4;
        float4 va, vb;
        if (c < C1) {
            va = *reinterpret_cast<const float4*>(&W1[(size_t)k * C1 + c]);
            vb = *reinterpret_cast<const float4*>(&W1[(size_t)(k + 1) * C1 + c]);
        } else {
            va = *reinterpret_cast<const float4*>(&W2[(size_t)k * C2 + (c - C1)]);
            vb = *reinterpret_cast<const float4*>(&W2[(size_t)(k + 1) * C2 + (c - C1)]);
        }
        wt[(c + 0) * KP + kp] = pack_bf2(va.x, vb.x);
        wt[(c + 1) * KP + kp] = pack_bf2(va.y, vb.y);
        wt[(c + 2) * KP + kp] = pack_bf2(va.z, vb.z);
        wt[(c + 3) * KP + kp] = pack_bf2(va.w, vb.w);
    }
    __syncthreads();

    // compute: wave strip = 16 rows, NT 16-col tiles, K in 32-steps
    const int rowbase = wave * 16;
    f32x4 acc[NT];
#pragma unroll
    for (int t = 0; t < NT; ++t) acc[t] = (f32x4){0.f, 0.f, 0.f, 0.f};

#pragma unroll
    for (int ks = 0; ks < KS; ++ks) {
        bf16x8 a = *reinterpret_cast<const bf16x8*>(&xb[(rowbase + m) * KP + ks * 16 + quad * 4]);
#pragma unroll
        for (int t = 0; t < NT; ++t) {
            bf16x8 b = *reinterpret_cast<const bf16x8*>(&wt[(t * 16 + m) * KP + ks * 16 + quad * 4]);
            acc[t] = __builtin_amdgcn_mfma_f32_16x16x32_bf16(a, b, acc[t], 0, 0, 0);
        }
    }

    // epilogue: D[q*4+reg][lane&15] per tile
#pragma unroll
    for (int t = 0; t < NT; ++t) {
        int c = t * 16 + m;
        float bias = (c >= C1) ? Bias[c - C1] : 0.f;
#pragma unroll
        for (int reg = 0; reg < 4; ++reg) {
            int rl = rowbase + quad * 4 + reg;
            int r = r0 + rl;
            if (r >= N) continue;
            float v = acc[t][reg];
            if (c < C1) {
                Y1b[(size_t)r * C1 + c] = bf16_of(v * dloc[rl]);
            } else {
                Y2[(size_t)r * C2 + (c - C1)] = v + bias;
            }
        }
    }
}

// ---------------- pull aggregation over pre-scaled bf16 H ----------------
//  Y[node] = relu(Y[node] + dinv[node] * sum_e H[srow[e]])
// Edge loop unrolled x4 (MLP=4; latency-bound, round-8/9 lesson).

template<int C>
__launch_bounds__(256)
__global__ void pull_bf16_kernel(const int* __restrict__ offsets,
                                 const int* __restrict__ srow,
                                 const float* __restrict__ dinv,
                                 const unsigned* __restrict__ H,   // bf16 [N][C], pre-scaled
                                 float* __restrict__ Y, int N) {
    constexpr int TPE = C / 4;             // lanes per node, 4 bf16 (uint2) each
    constexpr int CH = C / 2;              // uints per row
    int gid = blockIdx.x * blockDim.x + threadIdx.x;
    int node = gid / TPE;
    int lane = gid - node * TPE;
    if (node >= N) return;

    int e0 = offsets[node];
    int e1 = offsets[node + 1];
    float dc = dinv[node];

    float4 acc = make_float4(0.f, 0.f, 0.f, 0.f);
    int j = e0;
    for (; j + 4 <= e1; j += 4) {
        int r0 = srow[j + 0];
        int r1 = srow[j + 1];
        int r2 = srow[j + 2];
        int r3 = srow[j + 3];
        uint2 u0 = *reinterpret_cast<const uint2*>(&H[(size_t)r0 * CH + lane * 2]);
        uint2 u1 = *reinterpret_cast<const uint2*>(&H[(size_t)r1 * CH + lane * 2]);
        uint2 u2 = *reinterpret_cast<const uint2*>(&H[(size_t)r2 * CH + lane * 2]);
        uint2 u3 = *reinterpret_cast<const uint2*>(&H[(size_t)r3 * CH + lane * 2]);
        acc.x += (bf_lo(u0.x) + bf_lo(u1.x)) + (bf_lo(u2.x) + bf_lo(u3.x));
        acc.y += (bf_hi(u0.x) + bf_hi(u1.x)) + (bf_hi(u2.x) + bf_hi(u3.x));
        acc.z += (bf_lo(u0.y) + bf_lo(u1.y)) + (bf_lo(u2.y) + bf_lo(u3.y));
        acc.w += (bf_hi(u0.y) + bf_hi(u1.y)) + (bf_hi(u2.y) + bf_hi(u3.y));
    }
    for (; j < e1; ++j) {
        int r = srow[j];
        uint2 u = *reinterpret_cast<const uint2*>(&H[(size_t)r * CH + lane * 2]);
        acc.x += bf_lo(u.x);
        acc.y += bf_hi(u.x);
        acc.z += bf_lo(u.y);
        acc.w += bf_hi(u.y);
    }

    float4* Y4 = reinterpret_cast<float4*>(Y);
    size_t yi = (size_t)node * TPE + lane;
    float4 y = Y4[yi];
    y.x = fmaxf(fmaf(dc, acc.x, y.x), 0.f);
    y.y = fmaxf(fmaf(dc, acc.y, y.y), 0.f);
    y.z = fmaxf(fmaf(dc, acc.z, y.z), 0.f);
    y.w = fmaxf(fmaf(dc, acc.w, y.w), 0.f);
    Y4[yi] = y;
}

// ---------------- launcher ----------------

extern "C" void kernel_launch(void* const* d_in, const int* in_sizes, int n_in,
                              void* d_out, int out_size, void* d_ws, size_t ws_size,
                              hipStream_t stream) {
    const float* x       = (const float*)d_in[0];
    const int*   eidx    = (const int*)d_in[1];
    const float* w1_init = (const float*)d_in[2];
    const float* w1_root = (const float*)d_in[3];
    const float* b1      = (const float*)d_in[4];
    const float* w2_init = (const float*)d_in[5];
    const float* w2_root = (const float*)d_in[6];
    const float* b2      = (const float*)d_in[7];
    float* out = (float*)d_out;

    const int* rows = eidx;                // edge_index[0] (source)
    const int* cols = eidx + N_EDGES;      // edge_index[1] (target)

    // workspace layout (4-byte units)
    int* wsi = (int*)d_ws;
    int*      gcount  = wsi;                         //     784
    int*      boff    = wsi + 784;                   //     788 (NBUCK+1 = 783 used)
    int*      gcursor = wsi + 1572;                  //     788
    float*    dinv    = (float*)(wsi + 2360);        //   100,000
    int*      offsets = wsi + 102360;                //   100,004 (N_NODES+1 used)
    int*      srow    = wsi + 202364;                // 1,000,000
    unsigned* h0b     = (unsigned*)(wsi + 1202364);  // 3,200,000 uints (bf16 h, reused as h2b)
    int*      pedge   = wsi + 1202364;               // aliases h0b: dead before gemm L1
    float*    agg1    = (float*)(wsi + 4402364);     // 6,400,000
    unsigned* h2b     = h0b;
    // total 10,802,364 * 4 B = 43.2 MB

    // ---- graph prep: bucket partition -> sorted CSR + dinv (no global per-edge atomics) ----
    hipMemsetAsync(gcount, 0, 784 * sizeof(int), stream);
    bucket_count_kernel<<<128, 256, 0, stream>>>(cols, gcount, N_EDGES);
    scan_bucket_kernel<<<1, 1024, 0, stream>>>(gcount, boff, gcursor, offsets);
    bucket_scatter_kernel<<<128, 256, 0, stream>>>(rows, cols, gcursor, pedge, N_EDGES);
    bucket_sort_kernel<<<NBUCK, 256, 0, stream>>>(boff, pedge, srow, offsets, dinv);

    const int GGRID = cdiv(N_NODES, 64);   // 1563

    // ---- layer 1 ----
    gemm_mfma_fused_kernel<IN_CH, HID_CH, HID_CH><<<GGRID, 256, 0, stream>>>(
        x, w1_init, w1_root, b1, dinv, (unsigned short*)h0b, agg1, N_NODES);
    pull_bf16_kernel<HID_CH><<<cdiv(N_NODES * (HID_CH / 4), 256), 256, 0, stream>>>(
        offsets, srow, dinv, h0b, agg1, N_NODES);

    // ---- layer 2 ----
    gemm_mfma_fused_kernel<HID_CH, N_CLS, N_CLS><<<GGRID, 256, 0, stream>>>(
        agg1, w2_init, w2_root, b2, dinv, (unsigned short*)h2b, out, N_NODES);
    pull_bf16_kernel<N_CLS><<<cdiv(N_NODES * (N_CLS / 4), 256), 256, 0, stream>>>(
        offsets, srow, dinv, h2b, out, N_NODES);
}